// Round 1
// baseline (687.011 us; speedup 1.0000x reference)
//
#include <hip/hip_runtime.h>

typedef unsigned short u16;
typedef __attribute__((ext_vector_type(8))) __bf16 bf16x8;
typedef __attribute__((ext_vector_type(8))) short short8s;
typedef __attribute__((ext_vector_type(4))) float float4v;

// ---------- sizes ----------
static constexpr int NB = 4, NC = 256, NH = 64, NW = 64, NHW = 4096;
static constexpr size_t SZ_BF = (size_t)NB * NC * NHW * 2;   // 8 MB
static constexpr size_t SZ_F  = (size_t)NB * NC * NHW * 4;   // 16 MB
static constexpr size_t OFF_KBF   = 0;
static constexpr size_t OFF_VBF   = OFF_KBF + SZ_BF;
static constexpr size_t OFF_QBF   = OFF_VBF + SZ_BF;
static constexpr size_t OFF_QT    = OFF_QBF + SZ_BF;
static constexpr size_t OFF_KT    = OFF_QT + SZ_BF;
static constexpr size_t OFF_GT    = OFF_KT + SZ_BF;          // fp32 [B][N][C]
static constexpr size_t OFF_LOCAL = OFF_GT + SZ_F;           // fp32 [B][C][N]
static constexpr size_t OFF_HID   = OFF_LOCAL + SZ_F;        // fp32 [B][64][N]
static constexpr size_t OFF_FUSED = OFF_HID + (size_t)NB * 64 * NHW * 4;
static constexpr size_t OFF_GAP   = OFF_FUSED + SZ_F;
static constexpr size_t OFF_CW    = OFF_GAP + 4096;

__device__ __forceinline__ float b2f(u16 h) {
    union { float f; unsigned u; } v; v.u = ((unsigned)h) << 16; return v.f;
}
__device__ __forceinline__ u16 f2b(float f) {
    union { float f; unsigned u; } v; v.f = f;
    unsigned r = v.u + 0x7fffu + ((v.u >> 16) & 1u);
    return (u16)(r >> 16);
}

// ---------- depthwise 3x3: k and v (bf16 outputs) ----------
__global__ __launch_bounds__(256) void dw_kv(
    const float* __restrict__ x, const float* __restrict__ Wk, const float* __restrict__ bk,
    const float* __restrict__ Wv, const float* __restrict__ bv,
    u16* __restrict__ k_bf, u16* __restrict__ vN)
{
    int t = threadIdx.x;
    int xx0 = t & 63, cl = t >> 6;
    int y  = blockIdx.x;
    int c  = blockIdx.y * 4 + cl;
    int b  = blockIdx.z;
    const float* xb = x + ((size_t)b * NC + c) * NHW;
    float wk[9], wv[9];
#pragma unroll
    for (int i = 0; i < 9; i++) { wk[i] = Wk[c * 9 + i]; wv[i] = Wv[c * 9 + i]; }
    float ak = bk[c], av = bv[c];
#pragma unroll
    for (int ky = 0; ky < 3; ky++) {
        int yy = y + ky - 1;
        if (yy < 0 || yy > 63) continue;
#pragma unroll
        for (int kx = 0; kx < 3; kx++) {
            int xx = xx0 + kx - 1;
            if (xx < 0 || xx > 63) continue;
            float xv = xb[yy * 64 + xx];
            ak += wk[ky * 3 + kx] * xv;
            av += wv[ky * 3 + kx] * xv;
        }
    }
    size_t o = ((size_t)b * NC + c) * NHW + y * 64 + xx0;
    k_bf[o] = f2b(ak);
    vN[o]   = f2b(av);
}

// ---------- depthwise 3x3 on v (bf16 in, fp32 out) ----------
__global__ __launch_bounds__(256) void dw_local(
    const u16* __restrict__ vN, const float* __restrict__ Wl, const float* __restrict__ bl,
    float* __restrict__ local)
{
    int t = threadIdx.x;
    int xx0 = t & 63, cl = t >> 6;
    int y = blockIdx.x;
    int c = blockIdx.y * 4 + cl;
    int b = blockIdx.z;
    const u16* vb = vN + ((size_t)b * NC + c) * NHW;
    float wl[9];
#pragma unroll
    for (int i = 0; i < 9; i++) wl[i] = Wl[c * 9 + i];
    float a = bl[c];
#pragma unroll
    for (int ky = 0; ky < 3; ky++) {
        int yy = y + ky - 1;
        if (yy < 0 || yy > 63) continue;
#pragma unroll
        for (int kx = 0; kx < 3; kx++) {
            int xx = xx0 + kx - 1;
            if (xx < 0 || xx > 63) continue;
            a += wl[ky * 3 + kx] * b2f(vb[yy * 64 + xx]);
        }
    }
    local[((size_t)b * NC + c) * NHW + y * 64 + xx0] = a;
}

// ---------- generic 64x64-tile fp32 GEMM core ----------
template <int K>
__device__ __forceinline__ void gemm64(
    const float* __restrict__ A,   // [M][K] row-major, rows m0..m0+63
    const float* __restrict__ Xb,  // [K][4096]
    int m0, int n0, int t, float acc[4][4])
{
    __shared__ float As[16][68];
    __shared__ float Bs[16][68];
    const int tn = t & 15, tm = t >> 4;
    const int am = t >> 2, aj = (t & 3) * 4;
    const int bk_ = t >> 4, bn = (t & 15) * 4;
    for (int k0 = 0; k0 < K; k0 += 16) {
        float4 avv = *(const float4*)(A + (size_t)(m0 + am) * K + k0 + aj);
        float4 bvv = *(const float4*)(Xb + (size_t)(k0 + bk_) * NHW + n0 + bn);
        __syncthreads();
        As[aj + 0][am] = avv.x; As[aj + 1][am] = avv.y;
        As[aj + 2][am] = avv.z; As[aj + 3][am] = avv.w;
        *(float4*)&Bs[bk_][bn] = bvv;
        __syncthreads();
#pragma unroll
        for (int kk = 0; kk < 16; kk++) {
            float4 a = *(const float4*)&As[kk][tm * 4];
            float4 bb = *(const float4*)&Bs[kk][tn * 4];
#pragma unroll
            for (int i = 0; i < 4; i++)
#pragma unroll
                for (int j = 0; j < 4; j++)
                    acc[i][j] = fmaf(((const float*)&a)[i], ((const float*)&bb)[j], acc[i][j]);
        }
    }
}

// q = Wq @ x + bq  -> bf16 [B][C][N]
__global__ __launch_bounds__(256) void gemm_q(
    const float* __restrict__ Wq, const float* __restrict__ x, const float* __restrict__ bq,
    u16* __restrict__ q_bf)
{
    int n0 = blockIdx.x * 64, m0 = blockIdx.y * 64, b = blockIdx.z;
    float acc[4][4] = {};
    gemm64<256>(Wq, x + (size_t)b * NC * NHW, m0, n0, threadIdx.x, acc);
    int tn = threadIdx.x & 15, tm = threadIdx.x >> 4;
#pragma unroll
    for (int i = 0; i < 4; i++) {
        int m = m0 + tm * 4 + i;
        float bb = bq[m];
#pragma unroll
        for (int j = 0; j < 4; j++) {
            int n = n0 + tn * 4 + j;
            q_bf[((size_t)b * NC + m) * NHW + n] = f2b(acc[i][j] + bb);
        }
    }
}

// hid = relu(Ws1 @ local + bs1)  [B][64][N]
__global__ __launch_bounds__(256) void gemm_hid(
    const float* __restrict__ Ws1, const float* __restrict__ local, const float* __restrict__ bs1,
    float* __restrict__ hid)
{
    int n0 = blockIdx.x * 64, m0 = 0, b = blockIdx.z;
    float acc[4][4] = {};
    gemm64<256>(Ws1, local + (size_t)b * NC * NHW, m0, n0, threadIdx.x, acc);
    int tn = threadIdx.x & 15, tm = threadIdx.x >> 4;
#pragma unroll
    for (int i = 0; i < 4; i++) {
        int m = m0 + tm * 4 + i;
        float bb = bs1[m];
#pragma unroll
        for (int j = 0; j < 4; j++) {
            int n = n0 + tn * 4 + j;
            hid[((size_t)b * 64 + m) * NHW + n] = fmaxf(acc[i][j] + bb, 0.0f);
        }
    }
}

// fused = gT*cw + local*sigmoid(Ws2@hid + bs2)   [B][C][N]
__global__ __launch_bounds__(256) void gemm_swfused(
    const float* __restrict__ Ws2, const float* __restrict__ hid, const float* __restrict__ bs2,
    const float* __restrict__ gT, const float* __restrict__ local, const float* __restrict__ cw,
    float* __restrict__ fused)
{
    int n0 = blockIdx.x * 64, m0 = blockIdx.y * 64, b = blockIdx.z;
    float acc[4][4] = {};
    gemm64<64>(Ws2, hid + (size_t)b * 64 * NHW, m0, n0, threadIdx.x, acc);
    int tn = threadIdx.x & 15, tm = threadIdx.x >> 4;
#pragma unroll
    for (int i = 0; i < 4; i++) {
        int c = m0 + tm * 4 + i;
        float bb = bs2[c];
        float cwv = cw[b * NC + c];
#pragma unroll
        for (int j = 0; j < 4; j++) {
            int n = n0 + tn * 4 + j;
            float sw = 1.0f / (1.0f + __expf(-(acc[i][j] + bb)));
            float g = gT[((size_t)b * NHW + n) * NC + c];
            float lo = local[((size_t)b * NC + c) * NHW + n];
            fused[((size_t)b * NC + c) * NHW + n] = g * cwv + lo * sw;
        }
    }
}

// out = Wo @ fused + bo + x
__global__ __launch_bounds__(256) void gemm_out(
    const float* __restrict__ Wo, const float* __restrict__ fused, const float* __restrict__ bo,
    const float* __restrict__ x, float* __restrict__ out)
{
    int n0 = blockIdx.x * 64, m0 = blockIdx.y * 64, b = blockIdx.z;
    float acc[4][4] = {};
    gemm64<256>(Wo, fused + (size_t)b * NC * NHW, m0, n0, threadIdx.x, acc);
    int tn = threadIdx.x & 15, tm = threadIdx.x >> 4;
#pragma unroll
    for (int i = 0; i < 4; i++) {
        int o = m0 + tm * 4 + i;
        float bb = bo[o];
#pragma unroll
        for (int j = 0; j < 4; j++) {
            int n = n0 + tn * 4 + j;
            size_t idx = ((size_t)b * NC + o) * NHW + n;
            out[idx] = acc[i][j] + bb + x[idx];
        }
    }
}

// ---------- bf16 transpose [C][N] -> [N][C] for q and k ----------
__global__ __launch_bounds__(256) void transpose_bf(
    const u16* __restrict__ q_bf, const u16* __restrict__ k_bf,
    u16* __restrict__ qT, u16* __restrict__ kT)
{
    __shared__ u16 tile[64][72];
    int n0 = blockIdx.x * 64, c0 = blockIdx.y * 64;
    int zb = blockIdx.z, b = zb >> 1;
    const u16* src = (zb & 1) ? k_bf : q_bf;
    u16* dst = (zb & 1) ? kT : qT;
    src += (size_t)b * NC * NHW;
    dst += (size_t)b * NHW * NC;
    int t = threadIdx.x;
    int c = t >> 2, nb = (t & 3) * 16;
    *(short8s*)&tile[c][nb]     = *(const short8s*)(src + (size_t)(c0 + c) * NHW + n0 + nb);
    *(short8s*)&tile[c][nb + 8] = *(const short8s*)(src + (size_t)(c0 + c) * NHW + n0 + nb + 8);
    __syncthreads();
    int cl = t & 63, ng = t >> 6;
#pragma unroll
    for (int j = 0; j < 16; j++) {
        int n = ng * 16 + j;
        dst[(size_t)(n0 + n) * NC + c0 + cl] = tile[cl][n];
    }
}

// ---------- flash attention (no-max online softmax; logits tiny) ----------
__global__ __launch_bounds__(256) void attn_kernel(
    const u16* __restrict__ qT, const u16* __restrict__ kT,
    const u16* __restrict__ vN, float* __restrict__ gT)
{
    __shared__ u16 Kl[64 * 256];   // swizzled [n][c]; P aliased at w*1024
    __shared__ u16 Vl[256 * 64];   // swizzled [c][kv]

    const int b = blockIdx.y;
    const int n0 = blockIdx.x * 64;
    const int t = threadIdx.x;
    const int w = t >> 6, lane = t & 63;
    const int lm = lane & 15, quad = lane >> 4;

    const size_t bQ = (size_t)b * NHW * NC;
    const u16* qTb = qT + bQ;
    const u16* kTb = kT + bQ;
    const u16* vNb = vN + bQ;

    // Q fragments (A-operand): A[m=lm][k=quad*8+j], K-dim = 256 -> 8 frags
    bf16x8 aq[8];
    {
        int qrow = n0 + w * 16 + lm;
#pragma unroll
        for (int kt = 0; kt < 8; kt++)
            aq[kt] = *(const bf16x8*)(qTb + (size_t)qrow * NC + kt * 32 + quad * 8);
    }

    float4v oacc[16];
#pragma unroll
    for (int i = 0; i < 16; i++) oacc[i] = (float4v){0.f, 0.f, 0.f, 0.f};
    float lsum[4] = {0.f, 0.f, 0.f, 0.f};

    for (int kv0 = 0; kv0 < NHW; kv0 += 64) {
        __syncthreads();  // prior PV reads done before restage
        // stage K tile: 64 rows x 256 c, 16B chunks with XOR swizzle
#pragma unroll
        for (int i = 0; i < 8; i++) {
            int id = i * 256 + t;
            int n = id >> 5, cc = id & 31;
            short8s val = *(const short8s*)(kTb + (size_t)(kv0 + n) * NC + cc * 8);
            *(short8s*)&Kl[n * 256 + ((cc ^ (n & 31)) << 3)] = val;
        }
        // stage V tile: 256 c x 64 kv
#pragma unroll
        for (int i = 0; i < 8; i++) {
            int id = i * 256 + t;
            int c = id >> 3, ck = id & 7;
            short8s val = *(const short8s*)(vNb + (size_t)c * NHW + kv0 + ck * 8);
            *(short8s*)&Vl[c * 64 + ((ck ^ (c & 7)) << 3)] = val;
        }
        __syncthreads();
        // S = Q @ K^T : 16x64 per wave
        float4v sf[4];
#pragma unroll
        for (int nt = 0; nt < 4; nt++) {
            float4v acc = (float4v){0.f, 0.f, 0.f, 0.f};
            int n = nt * 16 + lm;
#pragma unroll
            for (int kt = 0; kt < 8; kt++) {
                int cc = kt * 4 + quad;
                bf16x8 bk = *(const bf16x8*)&Kl[n * 256 + ((cc ^ (n & 31)) << 3)];
                acc = __builtin_amdgcn_mfma_f32_16x16x32_bf16(aq[kt], bk, acc, 0, 0, 0);
            }
            sf[nt] = acc;
        }
        __syncthreads();  // all K reads done before P aliases Kl
        // exp (no max subtraction; logits bounded ~|0.2|)
        float rp[4] = {0.f, 0.f, 0.f, 0.f};
#pragma unroll
        for (int nt = 0; nt < 4; nt++)
#pragma unroll
            for (int r = 0; r < 4; r++) {
                float p = __expf(sf[nt][r] * 0.0625f);
                sf[nt][r] = p;
                rp[r] += p;
            }
#pragma unroll
        for (int off = 8; off >= 1; off >>= 1)
#pragma unroll
            for (int r = 0; r < 4; r++)
                rp[r] += __shfl_xor(rp[r], off, 64);
#pragma unroll
        for (int r = 0; r < 4; r++) lsum[r] += rp[r];
        // P (C-layout) -> LDS in A-operand layout, wave-private region
        u16* Pw = &Kl[w * 1024];
#pragma unroll
        for (int nt = 0; nt < 4; nt++) {
            int col = nt * 16 + lm;
            int ckc = col >> 3, cr = col & 7;
#pragma unroll
            for (int r = 0; r < 4; r++) {
                int row = quad * 4 + r;
                Pw[row * 64 + ((ckc ^ (row & 7)) << 3) + cr] = f2b(sf[nt][r]);
            }
        }
        __asm__ __volatile__("s_waitcnt lgkmcnt(0)" ::: "memory");
        // PV: O += P @ V
        bf16x8 pa[2];
#pragma unroll
        for (int kt2 = 0; kt2 < 2; kt2++) {
            int ck = kt2 * 4 + quad;
            pa[kt2] = *(const bf16x8*)&Pw[lm * 64 + ((ck ^ (lm & 7)) << 3)];
        }
#pragma unroll
        for (int ct = 0; ct < 16; ct++) {
            int c = ct * 16 + lm;
#pragma unroll
            for (int kt2 = 0; kt2 < 2; kt2++) {
                int ck = kt2 * 4 + quad;
                bf16x8 bv = *(const bf16x8*)&Vl[c * 64 + ((ck ^ (c & 7)) << 3)];
                oacc[ct] = __builtin_amdgcn_mfma_f32_16x16x32_bf16(pa[kt2], bv, oacc[ct], 0, 0, 0);
            }
        }
    }
    // epilogue: O / l -> gT [N][C]
    float* gTb = gT + (size_t)b * NHW * NC;
#pragma unroll
    for (int r = 0; r < 4; r++) {
        float inv = 1.0f / lsum[r];
        int grow = n0 + w * 16 + quad * 4 + r;
#pragma unroll
        for (int ct = 0; ct < 16; ct++)
            gTb[(size_t)grow * NC + ct * 16 + lm] = oacc[ct][r] * inv;
    }
}

// ---------- gap reduce + channel MLP ----------
__global__ __launch_bounds__(256) void gap_reduce(const float* __restrict__ gT, float* __restrict__ gap)
{
    int b = blockIdx.y, n0 = blockIdx.x * 64, t = threadIdx.x;
    const float* g = gT + ((size_t)b * NHW + n0) * NC;
    float acc = 0.f;
#pragma unroll 4
    for (int i = 0; i < 64; i++) acc += g[(size_t)i * NC + t];
    atomicAdd(&gap[b * NC + t], acc);
}

__global__ __launch_bounds__(256) void channel_mlp(
    const float* __restrict__ gap, const float* __restrict__ Wc1, const float* __restrict__ bc1,
    const float* __restrict__ Wc2, const float* __restrict__ bc2, float* __restrict__ cw)
{
    __shared__ float g[256];
    __shared__ float ph[32][9];
    __shared__ float h1[32];
    int t = threadIdx.x;
    for (int b = 0; b < 4; b++) {
        g[t] = gap[b * 256 + t] * (1.0f / 4096.0f);
        __syncthreads();
        {
            int h = t & 31, part = t >> 5;
            float s = 0.f;
            for (int c = part * 32; c < part * 32 + 32; c++) s += Wc1[h * 256 + c] * g[c];
            ph[h][part] = s;
        }
        __syncthreads();
        if (t < 32) {
            float s = bc1[t];
#pragma unroll
            for (int p = 0; p < 8; p++) s += ph[t][p];
            h1[t] = fmaxf(s, 0.f);
        }
        __syncthreads();
        float s = bc2[t];
#pragma unroll
        for (int j = 0; j < 32; j++) s += Wc2[t * 32 + j] * h1[j];
        cw[b * 256 + t] = 1.0f / (1.0f + __expf(-s));
        __syncthreads();
    }
}

extern "C" void kernel_launch(void* const* d_in, const int* in_sizes, int n_in,
                              void* d_out, int out_size, void* d_ws, size_t ws_size,
                              hipStream_t stream)
{
    const float* x   = (const float*)d_in[0];
    const float* Wq  = (const float*)d_in[1];
    const float* bq  = (const float*)d_in[2];
    const float* Wk  = (const float*)d_in[3];
    const float* bk  = (const float*)d_in[4];
    const float* Wv  = (const float*)d_in[5];
    const float* bv  = (const float*)d_in[6];
    const float* Wl  = (const float*)d_in[7];
    const float* bl  = (const float*)d_in[8];
    const float* Ws1 = (const float*)d_in[9];
    const float* bs1 = (const float*)d_in[10];
    const float* Ws2 = (const float*)d_in[11];
    const float* bs2 = (const float*)d_in[12];
    const float* Wc1 = (const float*)d_in[13];
    const float* bc1 = (const float*)d_in[14];
    const float* Wc2 = (const float*)d_in[15];
    const float* bc2 = (const float*)d_in[16];
    const float* Wo  = (const float*)d_in[17];
    const float* bo  = (const float*)d_in[18];
    float* out = (float*)d_out;

    char* ws = (char*)d_ws;
    u16* k_bf = (u16*)(ws + OFF_KBF);
    u16* vN   = (u16*)(ws + OFF_VBF);
    u16* q_bf = (u16*)(ws + OFF_QBF);
    u16* qT   = (u16*)(ws + OFF_QT);
    u16* kT   = (u16*)(ws + OFF_KT);
    float* gT    = (float*)(ws + OFF_GT);
    float* local = (float*)(ws + OFF_LOCAL);
    float* hid   = (float*)(ws + OFF_HID);
    float* fused = (float*)(ws + OFF_FUSED);
    float* gap   = (float*)(ws + OFF_GAP);
    float* cw    = (float*)(ws + OFF_CW);

    dw_kv<<<dim3(64, 64, 4), 256, 0, stream>>>(x, Wk, bk, Wv, bv, k_bf, vN);
    gemm_q<<<dim3(64, 4, 4), 256, 0, stream>>>(Wq, x, bq, q_bf);
    transpose_bf<<<dim3(64, 4, 8), 256, 0, stream>>>(q_bf, k_bf, qT, kT);
    dw_local<<<dim3(64, 64, 4), 256, 0, stream>>>(vN, Wl, bl, local);
    attn_kernel<<<dim3(64, 4), 256, 0, stream>>>(qT, kT, vN, gT);
    hipMemsetAsync(gap, 0, NB * NC * sizeof(float), stream);
    gap_reduce<<<dim3(64, 4), 256, 0, stream>>>(gT, gap);
    channel_mlp<<<1, 256, 0, stream>>>(gap, Wc1, bc1, Wc2, bc2, cw);
    gemm_hid<<<dim3(64, 1, 4), 256, 0, stream>>>(Ws1, local, bs1, hid);
    gemm_swfused<<<dim3(64, 4, 4), 256, 0, stream>>>(Ws2, hid, bs2, gT, local, cw, fused);
    gemm_out<<<dim3(64, 4, 4), 256, 0, stream>>>(Wo, fused, bo, x, out);
}

// Round 2
// 625.835 us; speedup vs baseline: 1.0978x; 1.0978x over previous
//
#include <hip/hip_runtime.h>
#include <stdint.h>

typedef unsigned short u16;
typedef __attribute__((ext_vector_type(8))) __bf16 bf16x8;
typedef __attribute__((ext_vector_type(8))) short short8s;
typedef __attribute__((ext_vector_type(4))) float float4v;

// ---------- sizes ----------
static constexpr int NB = 4, NC = 256, NH = 64, NW = 64, NHW = 4096;
static constexpr int BC = 32;        // kv tile
static constexpr int NKV = 4;        // kv split factor
static constexpr int KVCHUNK = NHW / NKV;   // 1024
static constexpr size_t SZ_BF = (size_t)NB * NC * NHW * 2;   // 8 MB
static constexpr size_t SZ_F  = (size_t)NB * NC * NHW * 4;   // 16 MB
static constexpr size_t OFF_KBF   = 0;
static constexpr size_t OFF_VBF   = OFF_KBF + SZ_BF;
static constexpr size_t OFF_QBF   = OFF_VBF + SZ_BF;
static constexpr size_t OFF_QT    = OFF_QBF + SZ_BF;
static constexpr size_t OFF_KT    = OFF_QT + SZ_BF;
static constexpr size_t OFF_GT    = OFF_KT + SZ_BF;          // fp32 [B][N][C]
static constexpr size_t OFF_LOCAL = OFF_GT + SZ_F;           // fp32 [B][C][N]
static constexpr size_t OFF_HID   = OFF_LOCAL + SZ_F;        // fp32 [B][64][N]
static constexpr size_t OFF_GAP   = OFF_HID + (size_t)NB * 64 * NHW * 4;
static constexpr size_t OFF_CW    = OFF_GAP + 64 * 1024;
static constexpr size_t OFF_LPART = OFF_CW + 64 * 1024;      // fp32 [B][NKV][N] = 256KB
static constexpr size_t OFF_FUSED = OFF_LPART + (size_t)NB * NKV * NHW * 4;
// Opart (bf16 [B][NKV][N][C] = 32MB) aliases FUSED (16MB) + 16MB beyond;
// consumed by attn_combine BEFORE gemm_swfused writes fused. Total ws ~109MB.
static constexpr size_t OFF_OPART = OFF_FUSED;

__device__ __forceinline__ float b2f(u16 h) {
    union { float f; unsigned u; } v; v.u = ((unsigned)h) << 16; return v.f;
}
__device__ __forceinline__ u16 f2b(float f) {
    union { float f; unsigned u; } v; v.f = f;
    unsigned r = v.u + 0x7fffu + ((v.u >> 16) & 1u);
    return (u16)(r >> 16);
}

// async global->LDS, 16B per lane; ldst must be wave-uniform (HW adds lane*16)
__device__ __forceinline__ void load_lds16(const void* gsrc, void* ldst) {
    __builtin_amdgcn_global_load_lds(
        (__attribute__((address_space(1))) void*)(uintptr_t)gsrc,
        (__attribute__((address_space(3))) void*)ldst,
        16, 0, 0);
}

// ---------- depthwise 3x3: k and v (bf16 outputs) ----------
__global__ __launch_bounds__(256) void dw_kv(
    const float* __restrict__ x, const float* __restrict__ Wk, const float* __restrict__ bk,
    const float* __restrict__ Wv, const float* __restrict__ bv,
    u16* __restrict__ k_bf, u16* __restrict__ vN)
{
    int t = threadIdx.x;
    int xx0 = t & 63, cl = t >> 6;
    int y  = blockIdx.x;
    int c  = blockIdx.y * 4 + cl;
    int b  = blockIdx.z;
    const float* xb = x + ((size_t)b * NC + c) * NHW;
    float wk[9], wv[9];
#pragma unroll
    for (int i = 0; i < 9; i++) { wk[i] = Wk[c * 9 + i]; wv[i] = Wv[c * 9 + i]; }
    float ak = bk[c], av = bv[c];
#pragma unroll
    for (int ky = 0; ky < 3; ky++) {
        int yy = y + ky - 1;
        if (yy < 0 || yy > 63) continue;
#pragma unroll
        for (int kx = 0; kx < 3; kx++) {
            int xx = xx0 + kx - 1;
            if (xx < 0 || xx > 63) continue;
            float xv = xb[yy * 64 + xx];
            ak += wk[ky * 3 + kx] * xv;
            av += wv[ky * 3 + kx] * xv;
        }
    }
    size_t o = ((size_t)b * NC + c) * NHW + y * 64 + xx0;
    k_bf[o] = f2b(ak);
    vN[o]   = f2b(av);
}

// ---------- depthwise 3x3 on v (bf16 in, fp32 out) ----------
__global__ __launch_bounds__(256) void dw_local(
    const u16* __restrict__ vN, const float* __restrict__ Wl, const float* __restrict__ bl,
    float* __restrict__ local)
{
    int t = threadIdx.x;
    int xx0 = t & 63, cl = t >> 6;
    int y = blockIdx.x;
    int c = blockIdx.y * 4 + cl;
    int b = blockIdx.z;
    const u16* vb = vN + ((size_t)b * NC + c) * NHW;
    float wl[9];
#pragma unroll
    for (int i = 0; i < 9; i++) wl[i] = Wl[c * 9 + i];
    float a = bl[c];
#pragma unroll
    for (int ky = 0; ky < 3; ky++) {
        int yy = y + ky - 1;
        if (yy < 0 || yy > 63) continue;
#pragma unroll
        for (int kx = 0; kx < 3; kx++) {
            int xx = xx0 + kx - 1;
            if (xx < 0 || xx > 63) continue;
            a += wl[ky * 3 + kx] * b2f(vb[yy * 64 + xx]);
        }
    }
    local[((size_t)b * NC + c) * NHW + y * 64 + xx0] = a;
}

// ---------- generic 64x64-tile fp32 GEMM core ----------
template <int K>
__device__ __forceinline__ void gemm64(
    const float* __restrict__ A,   // [M][K] row-major, rows m0..m0+63
    const float* __restrict__ Xb,  // [K][4096]
    int m0, int n0, int t, float acc[4][4])
{
    __shared__ float As[16][68];
    __shared__ float Bs[16][68];
    const int tn = t & 15, tm = t >> 4;
    const int am = t >> 2, aj = (t & 3) * 4;
    const int bk_ = t >> 4, bn = (t & 15) * 4;
    for (int k0 = 0; k0 < K; k0 += 16) {
        float4 avv = *(const float4*)(A + (size_t)(m0 + am) * K + k0 + aj);
        float4 bvv = *(const float4*)(Xb + (size_t)(k0 + bk_) * NHW + n0 + bn);
        __syncthreads();
        As[aj + 0][am] = avv.x; As[aj + 1][am] = avv.y;
        As[aj + 2][am] = avv.z; As[aj + 3][am] = avv.w;
        *(float4*)&Bs[bk_][bn] = bvv;
        __syncthreads();
#pragma unroll
        for (int kk = 0; kk < 16; kk++) {
            float4 a = *(const float4*)&As[kk][tm * 4];
            float4 bb = *(const float4*)&Bs[kk][tn * 4];
#pragma unroll
            for (int i = 0; i < 4; i++)
#pragma unroll
                for (int j = 0; j < 4; j++)
                    acc[i][j] = fmaf(((const float*)&a)[i], ((const float*)&bb)[j], acc[i][j]);
        }
    }
}

// q = Wq @ x + bq  -> bf16 [B][C][N]
__global__ __launch_bounds__(256) void gemm_q(
    const float* __restrict__ Wq, const float* __restrict__ x, const float* __restrict__ bq,
    u16* __restrict__ q_bf)
{
    int n0 = blockIdx.x * 64, m0 = blockIdx.y * 64, b = blockIdx.z;
    float acc[4][4] = {};
    gemm64<256>(Wq, x + (size_t)b * NC * NHW, m0, n0, threadIdx.x, acc);
    int tn = threadIdx.x & 15, tm = threadIdx.x >> 4;
#pragma unroll
    for (int i = 0; i < 4; i++) {
        int m = m0 + tm * 4 + i;
        float bb = bq[m];
#pragma unroll
        for (int j = 0; j < 4; j++) {
            int n = n0 + tn * 4 + j;
            q_bf[((size_t)b * NC + m) * NHW + n] = f2b(acc[i][j] + bb);
        }
    }
}

// hid = relu(Ws1 @ local + bs1)  [B][64][N]
__global__ __launch_bounds__(256) void gemm_hid(
    const float* __restrict__ Ws1, const float* __restrict__ local, const float* __restrict__ bs1,
    float* __restrict__ hid)
{
    int n0 = blockIdx.x * 64, m0 = 0, b = blockIdx.z;
    float acc[4][4] = {};
    gemm64<256>(Ws1, local + (size_t)b * NC * NHW, m0, n0, threadIdx.x, acc);
    int tn = threadIdx.x & 15, tm = threadIdx.x >> 4;
#pragma unroll
    for (int i = 0; i < 4; i++) {
        int m = m0 + tm * 4 + i;
        float bb = bs1[m];
#pragma unroll
        for (int j = 0; j < 4; j++) {
            int n = n0 + tn * 4 + j;
            hid[((size_t)b * 64 + m) * NHW + n] = fmaxf(acc[i][j] + bb, 0.0f);
        }
    }
}

// fused = gT*cw + local*sigmoid(Ws2@hid + bs2)   [B][C][N]
__global__ __launch_bounds__(256) void gemm_swfused(
    const float* __restrict__ Ws2, const float* __restrict__ hid, const float* __restrict__ bs2,
    const float* __restrict__ gT, const float* __restrict__ local, const float* __restrict__ cw,
    float* __restrict__ fused)
{
    int n0 = blockIdx.x * 64, m0 = blockIdx.y * 64, b = blockIdx.z;
    float acc[4][4] = {};
    gemm64<64>(Ws2, hid + (size_t)b * 64 * NHW, m0, n0, threadIdx.x, acc);
    int tn = threadIdx.x & 15, tm = threadIdx.x >> 4;
#pragma unroll
    for (int i = 0; i < 4; i++) {
        int c = m0 + tm * 4 + i;
        float bb = bs2[c];
        float cwv = cw[b * NC + c];
#pragma unroll
        for (int j = 0; j < 4; j++) {
            int n = n0 + tn * 4 + j;
            float sw = 1.0f / (1.0f + __expf(-(acc[i][j] + bb)));
            float g = gT[((size_t)b * NHW + n) * NC + c];
            float lo = local[((size_t)b * NC + c) * NHW + n];
            fused[((size_t)b * NC + c) * NHW + n] = g * cwv + lo * sw;
        }
    }
}

// out = Wo @ fused + bo + x
__global__ __launch_bounds__(256) void gemm_out(
    const float* __restrict__ Wo, const float* __restrict__ fused, const float* __restrict__ bo,
    const float* __restrict__ x, float* __restrict__ out)
{
    int n0 = blockIdx.x * 64, m0 = blockIdx.y * 64, b = blockIdx.z;
    float acc[4][4] = {};
    gemm64<256>(Wo, fused + (size_t)b * NC * NHW, m0, n0, threadIdx.x, acc);
    int tn = threadIdx.x & 15, tm = threadIdx.x >> 4;
#pragma unroll
    for (int i = 0; i < 4; i++) {
        int o = m0 + tm * 4 + i;
        float bb = bo[o];
#pragma unroll
        for (int j = 0; j < 4; j++) {
            int n = n0 + tn * 4 + j;
            size_t idx = ((size_t)b * NC + o) * NHW + n;
            out[idx] = acc[i][j] + bb + x[idx];
        }
    }
}

// ---------- bf16 transpose [C][N] -> [N][C] for q and k ----------
__global__ __launch_bounds__(256) void transpose_bf(
    const u16* __restrict__ q_bf, const u16* __restrict__ k_bf,
    u16* __restrict__ qT, u16* __restrict__ kT)
{
    __shared__ u16 tile[64][72];
    int n0 = blockIdx.x * 64, c0 = blockIdx.y * 64;
    int zb = blockIdx.z, b = zb >> 1;
    const u16* src = (zb & 1) ? k_bf : q_bf;
    u16* dst = (zb & 1) ? kT : qT;
    src += (size_t)b * NC * NHW;
    dst += (size_t)b * NHW * NC;
    int t = threadIdx.x;
    int c = t >> 2, nb = (t & 3) * 16;
    *(short8s*)&tile[c][nb]     = *(const short8s*)(src + (size_t)(c0 + c) * NHW + n0 + nb);
    *(short8s*)&tile[c][nb + 8] = *(const short8s*)(src + (size_t)(c0 + c) * NHW + n0 + nb + 8);
    __syncthreads();
    int cl = t & 63, ng = t >> 6;
#pragma unroll
    for (int j = 0; j < 16; j++) {
        int n = ng * 16 + j;
        dst[(size_t)(n0 + n) * NC + c0 + cl] = tile[cl][n];
    }
}

// ---------- flash attention, kv-split (no-max online softmax; logits tiny) ----------
// grid (64 qtiles, NKV kv-chunks, B). Partials: Opart bf16, lpart fp32.
__global__ __launch_bounds__(256, 4) void attn_split(
    const u16* __restrict__ qT, const u16* __restrict__ kT,
    const u16* __restrict__ vN, u16* __restrict__ Opart, float* __restrict__ lpart)
{
    __shared__ u16 Kl[BC * 256];     // 16KB: granule g=n*32+jj holds (n, cc=jj^n)
    __shared__ u16 Vl[256 * BC];     // 16KB: granule g=c*4+jj holds (c, ck=(jj-(c>>1))&3)
    __shared__ u16 Pl[4][16 * BC];   // 4KB wave-private P

    const int b = blockIdx.z;
    const int jc = blockIdx.y;
    const int n0 = blockIdx.x * 64;
    const int t = threadIdx.x;
    const int w = t >> 6, lane = t & 63;
    const int lm = lane & 15, quad = lane >> 4;

    const size_t bQ = (size_t)b * NHW * NC;
    const u16* qTb = qT + bQ;
    const u16* kTb = kT + bQ;
    const u16* vNb = vN + bQ;

    // Q fragments (A-operand): A[m=lm][k=quad*8+j], K-dim = 256 -> 8 frags
    bf16x8 aq[8];
    {
        int qrow = n0 + w * 16 + lm;
#pragma unroll
        for (int kt = 0; kt < 8; kt++)
            aq[kt] = *(const bf16x8*)(qTb + (size_t)qrow * NC + kt * 32 + quad * 8);
    }

    float4v oacc[16];
#pragma unroll
    for (int i = 0; i < 16; i++) oacc[i] = (float4v){0.f, 0.f, 0.f, 0.f};
    float lsum[4] = {0.f, 0.f, 0.f, 0.f};

    const int kvbeg = jc * KVCHUNK;
    for (int kv0 = kvbeg; kv0 < kvbeg + KVCHUNK; kv0 += BC) {
        __syncthreads();   // prior LDS reads done before restage
        // stage K tile (swizzle applied on source address; LDS dest lane-contiguous)
#pragma unroll
        for (int i = 0; i < 4; i++) {
            int g = (w * 4 + i) * 64 + lane;
            int n = g >> 5, jj = g & 31, cc = jj ^ n;
            load_lds16(kTb + (size_t)(kv0 + n) * NC + cc * 8,
                       (char*)Kl + (w * 4 + i) * 1024);
        }
        // stage V tile
#pragma unroll
        for (int i = 0; i < 4; i++) {
            int g = (w * 4 + i) * 64 + lane;
            int c = g >> 2, jj = g & 3, ck = (jj - (c >> 1)) & 3;
            load_lds16(vNb + (size_t)c * NHW + kv0 + ck * 8,
                       (char*)Vl + (w * 4 + i) * 1024);
        }
        __syncthreads();   // staging visible (vmcnt drained by barrier)

        // S = Q @ K^T : 16x32 per wave
        float4v sf[2];
#pragma unroll
        for (int nt = 0; nt < 2; nt++) {
            float4v acc = (float4v){0.f, 0.f, 0.f, 0.f};
            int n = nt * 16 + lm;
#pragma unroll
            for (int kt = 0; kt < 8; kt++) {
                int cc = kt * 4 + quad;
                bf16x8 bk = *(const bf16x8*)&Kl[(n * 32 + (cc ^ n)) * 8];
                acc = __builtin_amdgcn_mfma_f32_16x16x32_bf16(aq[kt], bk, acc, 0, 0, 0);
            }
            sf[nt] = acc;
        }
        // exp (no max subtraction; logits bounded ~|0.2|) + row sums
        float rp[4] = {0.f, 0.f, 0.f, 0.f};
#pragma unroll
        for (int nt = 0; nt < 2; nt++)
#pragma unroll
            for (int r = 0; r < 4; r++) {
                float p = __expf(sf[nt][r] * 0.0625f);
                sf[nt][r] = p;
                rp[r] += p;
            }
#pragma unroll
        for (int off = 8; off >= 1; off >>= 1)
#pragma unroll
            for (int r = 0; r < 4; r++)
                rp[r] += __shfl_xor(rp[r], off, 64);
#pragma unroll
        for (int r = 0; r < 4; r++) lsum[r] += rp[r];

        // P (C-layout) -> wave-private LDS, A-operand layout w/ rotate swizzle
        u16* Pw = &Pl[w][0];
#pragma unroll
        for (int nt = 0; nt < 2; nt++) {
            int col = nt * 16 + lm;
            int cg = col >> 3, cr = col & 7;
#pragma unroll
            for (int r = 0; r < 4; r++) {
                int row = quad * 4 + r;
                int sg = (cg + (row >> 1)) & 3;
                Pw[row * 32 + sg * 8 + cr] = f2b(sf[nt][r]);
            }
        }
        __asm__ __volatile__("s_waitcnt lgkmcnt(0)" ::: "memory");
        // PV: O += P @ V  (K-dim = 32 -> one A frag)
        bf16x8 pa = *(const bf16x8*)&Pw[lm * 32 + (((quad + (lm >> 1)) & 3)) * 8];
#pragma unroll
        for (int ct = 0; ct < 16; ct++) {
            int c = ct * 16 + lm;
            bf16x8 bv = *(const bf16x8*)&Vl[c * 32 + (((quad + (c >> 1)) & 3)) * 8];
            oacc[ct] = __builtin_amdgcn_mfma_f32_16x16x32_bf16(pa, bv, oacc[ct], 0, 0, 0);
        }
    }
    // epilogue: partial O (bf16) + partial l
    u16* Ob = Opart + ((size_t)(b * NKV + jc) * NHW + n0 + w * 16) * NC;
#pragma unroll
    for (int r = 0; r < 4; r++) {
        int row = quad * 4 + r;
#pragma unroll
        for (int ct = 0; ct < 16; ct++)
            Ob[(size_t)row * NC + ct * 16 + lm] = f2b(oacc[ct][r]);
        if (lm == 0)
            lpart[(size_t)(b * NKV + jc) * NHW + n0 + w * 16 + row] = lsum[r];
    }
}

// ---------- combine kv-split partials: gT = sum(Opart)/sum(lpart) ----------
__global__ __launch_bounds__(256) void attn_combine(
    const u16* __restrict__ Opart, const float* __restrict__ lpart, float* __restrict__ gT)
{
    int b = blockIdx.y;
    int n = blockIdx.x * 8 + (threadIdx.x >> 5);
    int c0 = (threadIdx.x & 31) * 8;
    float acc[8] = {};
    float l = 0.f;
#pragma unroll
    for (int j = 0; j < NKV; j++) {
        const u16* op = Opart + ((size_t)(b * NKV + j) * NHW + n) * NC + c0;
        short8s v = *(const short8s*)op;
#pragma unroll
        for (int i = 0; i < 8; i++) acc[i] += b2f(((const u16*)&v)[i]);
        l += lpart[(size_t)(b * NKV + j) * NHW + n];
    }
    float inv = 1.0f / l;
    float* g = gT + ((size_t)b * NHW + n) * NC + c0;
#pragma unroll
    for (int i = 0; i < 8; i++) acc[i] *= inv;
    *(float4*)&g[0] = make_float4(acc[0], acc[1], acc[2], acc[3]);
    *(float4*)&g[4] = make_float4(acc[4], acc[5], acc[6], acc[7]);
}

// ---------- gap reduce + channel MLP ----------
__global__ __launch_bounds__(256) void gap_reduce(const float* __restrict__ gT, float* __restrict__ gap)
{
    int b = blockIdx.y, n0 = blockIdx.x * 64, t = threadIdx.x;
    const float* g = gT + ((size_t)b * NHW + n0) * NC;
    float acc = 0.f;
#pragma unroll 4
    for (int i = 0; i < 64; i++) acc += g[(size_t)i * NC + t];
    atomicAdd(&gap[b * NC + t], acc);
}

__global__ __launch_bounds__(256) void channel_mlp(
    const float* __restrict__ gap, const float* __restrict__ Wc1, const float* __restrict__ bc1,
    const float* __restrict__ Wc2, const float* __restrict__ bc2, float* __restrict__ cw)
{
    __shared__ float g[256];
    __shared__ float ph[32][9];
    __shared__ float h1[32];
    int t = threadIdx.x;
    for (int b = 0; b < 4; b++) {
        g[t] = gap[b * 256 + t] * (1.0f / 4096.0f);
        __syncthreads();
        {
            int h = t & 31, part = t >> 5;
            float s = 0.f;
            for (int c = part * 32; c < part * 32 + 32; c++) s += Wc1[h * 256 + c] * g[c];
            ph[h][part] = s;
        }
        __syncthreads();
        if (t < 32) {
            float s = bc1[t];
#pragma unroll
            for (int p = 0; p < 8; p++) s += ph[t][p];
            h1[t] = fmaxf(s, 0.f);
        }
        __syncthreads();
        float s = bc2[t];
#pragma unroll
        for (int j = 0; j < 32; j++) s += Wc2[t * 32 + j] * h1[j];
        cw[b * 256 + t] = 1.0f / (1.0f + __expf(-s));
        __syncthreads();
    }
}

extern "C" void kernel_launch(void* const* d_in, const int* in_sizes, int n_in,
                              void* d_out, int out_size, void* d_ws, size_t ws_size,
                              hipStream_t stream)
{
    const float* x   = (const float*)d_in[0];
    const float* Wq  = (const float*)d_in[1];
    const float* bq  = (const float*)d_in[2];
    const float* Wk  = (const float*)d_in[3];
    const float* bk  = (const float*)d_in[4];
    const float* Wv  = (const float*)d_in[5];
    const float* bv  = (const float*)d_in[6];
    const float* Wl  = (const float*)d_in[7];
    const float* bl  = (const float*)d_in[8];
    const float* Ws1 = (const float*)d_in[9];
    const float* bs1 = (const float*)d_in[10];
    const float* Ws2 = (const float*)d_in[11];
    const float* bs2 = (const float*)d_in[12];
    const float* Wc1 = (const float*)d_in[13];
    const float* bc1 = (const float*)d_in[14];
    const float* Wc2 = (const float*)d_in[15];
    const float* bc2 = (const float*)d_in[16];
    const float* Wo  = (const float*)d_in[17];
    const float* bo  = (const float*)d_in[18];
    float* out = (float*)d_out;

    char* ws = (char*)d_ws;
    u16* k_bf = (u16*)(ws + OFF_KBF);
    u16* vN   = (u16*)(ws + OFF_VBF);
    u16* q_bf = (u16*)(ws + OFF_QBF);
    u16* qT   = (u16*)(ws + OFF_QT);
    u16* kT   = (u16*)(ws + OFF_KT);
    float* gT    = (float*)(ws + OFF_GT);
    float* local = (float*)(ws + OFF_LOCAL);
    float* hid   = (float*)(ws + OFF_HID);
    float* fused = (float*)(ws + OFF_FUSED);
    float* gap   = (float*)(ws + OFF_GAP);
    float* cw    = (float*)(ws + OFF_CW);
    u16* Opart   = (u16*)(ws + OFF_OPART);
    float* lpart = (float*)(ws + OFF_LPART);

    dw_kv<<<dim3(64, 64, 4), 256, 0, stream>>>(x, Wk, bk, Wv, bv, k_bf, vN);
    gemm_q<<<dim3(64, 4, 4), 256, 0, stream>>>(Wq, x, bq, q_bf);
    transpose_bf<<<dim3(64, 4, 8), 256, 0, stream>>>(q_bf, k_bf, qT, kT);
    dw_local<<<dim3(64, 64, 4), 256, 0, stream>>>(vN, Wl, bl, local);
    attn_split<<<dim3(64, NKV, 4), 256, 0, stream>>>(qT, kT, vN, Opart, lpart);
    attn_combine<<<dim3(NHW / 8, 4), 256, 0, stream>>>(Opart, lpart, gT);
    hipMemsetAsync(gap, 0, NB * NC * sizeof(float), stream);
    gap_reduce<<<dim3(64, 4), 256, 0, stream>>>(gT, gap);
    channel_mlp<<<1, 256, 0, stream>>>(gap, Wc1, bc1, Wc2, bc2, cw);
    gemm_hid<<<dim3(64, 1, 4), 256, 0, stream>>>(Ws1, local, bs1, hid);
    gemm_swfused<<<dim3(64, 4, 4), 256, 0, stream>>>(Ws2, hid, bs2, gT, local, cw, fused);
    gemm_out<<<dim3(64, 4, 4), 256, 0, stream>>>(Wo, fused, bo, x, out);
}

// Round 3
// 406.464 us; speedup vs baseline: 1.6902x; 1.5397x over previous
//
#include <hip/hip_runtime.h>
#include <stdint.h>

typedef unsigned short u16;
typedef __attribute__((ext_vector_type(8))) __bf16 bf16x8;
typedef __attribute__((ext_vector_type(8))) short short8s;
typedef __attribute__((ext_vector_type(4))) float float4v;

// ---------- sizes ----------
static constexpr int NB = 4, NC = 256, NH = 64, NW = 64, NHW = 4096;
static constexpr int BC = 32;        // kv tile
static constexpr int NKV = 4;        // kv split factor
static constexpr int KVCHUNK = NHW / NKV;   // 1024
static constexpr size_t SZ_BF = (size_t)NB * NC * NHW * 2;   // 8 MB
static constexpr size_t SZ_F  = (size_t)NB * NC * NHW * 4;   // 16 MB
static constexpr size_t OFF_KBF   = 0;
static constexpr size_t OFF_VBF   = OFF_KBF + SZ_BF;
static constexpr size_t OFF_QBF   = OFF_VBF + SZ_BF;
static constexpr size_t OFF_QT    = OFF_QBF + SZ_BF;
static constexpr size_t OFF_KT    = OFF_QT + SZ_BF;
static constexpr size_t OFF_GT    = OFF_KT + SZ_BF;          // fp32 [B][N][C]
static constexpr size_t OFF_LOCAL = OFF_GT + SZ_F;           // fp32 [B][C][N]
static constexpr size_t OFF_HID   = OFF_LOCAL + SZ_F;        // fp32 [B][64][N]
static constexpr size_t OFF_GAP   = OFF_HID + (size_t)NB * 64 * NHW * 4;
static constexpr size_t OFF_CW    = OFF_GAP + 64 * 1024;
static constexpr size_t OFF_LPART = OFF_CW + 64 * 1024;      // fp32 [B][NKV][N] = 256KB
static constexpr size_t OFF_FUSED = OFF_LPART + (size_t)NB * NKV * NHW * 4;
// Opart (bf16 [B][NKV][N][C] = 32MB) aliases FUSED (16MB) + 16MB beyond;
// consumed by attn_combine BEFORE gemm_swfused writes fused.
static constexpr size_t OFF_OPART = OFF_FUSED;

__device__ __forceinline__ float b2f(u16 h) {
    union { float f; unsigned u; } v; v.u = ((unsigned)h) << 16; return v.f;
}
__device__ __forceinline__ u16 f2b(float f) {
    union { float f; unsigned u; } v; v.f = f;
    unsigned r = v.u + 0x7fffu + ((v.u >> 16) & 1u);
    return (u16)(r >> 16);
}

// async global->LDS, 16B per lane; ldst must be wave-uniform (HW adds lane*16)
__device__ __forceinline__ void load_lds16(const void* gsrc, void* ldst) {
    __builtin_amdgcn_global_load_lds(
        (__attribute__((address_space(1))) void*)(uintptr_t)gsrc,
        (__attribute__((address_space(3))) void*)ldst,
        16, 0, 0);
}

// ---------- depthwise 3x3: k and v (bf16 outputs) ----------
__global__ __launch_bounds__(256) void dw_kv(
    const float* __restrict__ x, const float* __restrict__ Wk, const float* __restrict__ bk,
    const float* __restrict__ Wv, const float* __restrict__ bv,
    u16* __restrict__ k_bf, u16* __restrict__ vN)
{
    int t = threadIdx.x;
    int xx0 = t & 63, cl = t >> 6;
    int y  = blockIdx.x;
    int c  = blockIdx.y * 4 + cl;
    int b  = blockIdx.z;
    const float* xb = x + ((size_t)b * NC + c) * NHW;
    float wk[9], wv[9];
#pragma unroll
    for (int i = 0; i < 9; i++) { wk[i] = Wk[c * 9 + i]; wv[i] = Wv[c * 9 + i]; }
    float ak = bk[c], av = bv[c];
#pragma unroll
    for (int ky = 0; ky < 3; ky++) {
        int yy = y + ky - 1;
        if (yy < 0 || yy > 63) continue;
#pragma unroll
        for (int kx = 0; kx < 3; kx++) {
            int xx = xx0 + kx - 1;
            if (xx < 0 || xx > 63) continue;
            float xv = xb[yy * 64 + xx];
            ak += wk[ky * 3 + kx] * xv;
            av += wv[ky * 3 + kx] * xv;
        }
    }
    size_t o = ((size_t)b * NC + c) * NHW + y * 64 + xx0;
    k_bf[o] = f2b(ak);
    vN[o]   = f2b(av);
}

// ---------- depthwise 3x3 on v (bf16 in, fp32 out) ----------
__global__ __launch_bounds__(256) void dw_local(
    const u16* __restrict__ vN, const float* __restrict__ Wl, const float* __restrict__ bl,
    float* __restrict__ local)
{
    int t = threadIdx.x;
    int xx0 = t & 63, cl = t >> 6;
    int y = blockIdx.x;
    int c = blockIdx.y * 4 + cl;
    int b = blockIdx.z;
    const u16* vb = vN + ((size_t)b * NC + c) * NHW;
    float wl[9];
#pragma unroll
    for (int i = 0; i < 9; i++) wl[i] = Wl[c * 9 + i];
    float a = bl[c];
#pragma unroll
    for (int ky = 0; ky < 3; ky++) {
        int yy = y + ky - 1;
        if (yy < 0 || yy > 63) continue;
#pragma unroll
        for (int kx = 0; kx < 3; kx++) {
            int xx = xx0 + kx - 1;
            if (xx < 0 || xx > 63) continue;
            a += wl[ky * 3 + kx] * b2f(vb[yy * 64 + xx]);
        }
    }
    local[((size_t)b * NC + c) * NHW + y * 64 + xx0] = a;
}

// ---------- generic 64x64-tile fp32 GEMM core ----------
template <int K>
__device__ __forceinline__ void gemm64(
    const float* __restrict__ A,   // [M][K] row-major, rows m0..m0+63
    const float* __restrict__ Xb,  // [K][4096]
    int m0, int n0, int t, float acc[4][4])
{
    __shared__ float As[16][68];
    __shared__ float Bs[16][68];
    const int tn = t & 15, tm = t >> 4;
    const int am = t >> 2, aj = (t & 3) * 4;
    const int bk_ = t >> 4, bn = (t & 15) * 4;
    for (int k0 = 0; k0 < K; k0 += 16) {
        float4 avv = *(const float4*)(A + (size_t)(m0 + am) * K + k0 + aj);
        float4 bvv = *(const float4*)(Xb + (size_t)(k0 + bk_) * NHW + n0 + bn);
        __syncthreads();
        As[aj + 0][am] = avv.x; As[aj + 1][am] = avv.y;
        As[aj + 2][am] = avv.z; As[aj + 3][am] = avv.w;
        *(float4*)&Bs[bk_][bn] = bvv;
        __syncthreads();
#pragma unroll
        for (int kk = 0; kk < 16; kk++) {
            float4 a = *(const float4*)&As[kk][tm * 4];
            float4 bb = *(const float4*)&Bs[kk][tn * 4];
#pragma unroll
            for (int i = 0; i < 4; i++)
#pragma unroll
                for (int j = 0; j < 4; j++)
                    acc[i][j] = fmaf(((const float*)&a)[i], ((const float*)&bb)[j], acc[i][j]);
        }
    }
}

// q = Wq @ x + bq  -> bf16 [B][C][N]
__global__ __launch_bounds__(256) void gemm_q(
    const float* __restrict__ Wq, const float* __restrict__ x, const float* __restrict__ bq,
    u16* __restrict__ q_bf)
{
    int n0 = blockIdx.x * 64, m0 = blockIdx.y * 64, b = blockIdx.z;
    float acc[4][4] = {};
    gemm64<256>(Wq, x + (size_t)b * NC * NHW, m0, n0, threadIdx.x, acc);
    int tn = threadIdx.x & 15, tm = threadIdx.x >> 4;
#pragma unroll
    for (int i = 0; i < 4; i++) {
        int m = m0 + tm * 4 + i;
        float bb = bq[m];
#pragma unroll
        for (int j = 0; j < 4; j++) {
            int n = n0 + tn * 4 + j;
            q_bf[((size_t)b * NC + m) * NHW + n] = f2b(acc[i][j] + bb);
        }
    }
}

// hid = relu(Ws1 @ local + bs1)  [B][64][N]
__global__ __launch_bounds__(256) void gemm_hid(
    const float* __restrict__ Ws1, const float* __restrict__ local, const float* __restrict__ bs1,
    float* __restrict__ hid)
{
    int n0 = blockIdx.x * 64, m0 = 0, b = blockIdx.z;
    float acc[4][4] = {};
    gemm64<256>(Ws1, local + (size_t)b * NC * NHW, m0, n0, threadIdx.x, acc);
    int tn = threadIdx.x & 15, tm = threadIdx.x >> 4;
#pragma unroll
    for (int i = 0; i < 4; i++) {
        int m = m0 + tm * 4 + i;
        float bb = bs1[m];
#pragma unroll
        for (int j = 0; j < 4; j++) {
            int n = n0 + tn * 4 + j;
            hid[((size_t)b * 64 + m) * NHW + n] = fmaxf(acc[i][j] + bb, 0.0f);
        }
    }
}

// fused = gT*cw + local*sigmoid(Ws2@hid + bs2)   [B][C][N]
__global__ __launch_bounds__(256) void gemm_swfused(
    const float* __restrict__ Ws2, const float* __restrict__ hid, const float* __restrict__ bs2,
    const float* __restrict__ gT, const float* __restrict__ local, const float* __restrict__ cw,
    float* __restrict__ fused)
{
    int n0 = blockIdx.x * 64, m0 = blockIdx.y * 64, b = blockIdx.z;
    float acc[4][4] = {};
    gemm64<64>(Ws2, hid + (size_t)b * 64 * NHW, m0, n0, threadIdx.x, acc);
    int tn = threadIdx.x & 15, tm = threadIdx.x >> 4;
#pragma unroll
    for (int i = 0; i < 4; i++) {
        int c = m0 + tm * 4 + i;
        float bb = bs2[c];
        float cwv = cw[b * NC + c];
#pragma unroll
        for (int j = 0; j < 4; j++) {
            int n = n0 + tn * 4 + j;
            float sw = 1.0f / (1.0f + __expf(-(acc[i][j] + bb)));
            float g = gT[((size_t)b * NHW + n) * NC + c];
            float lo = local[((size_t)b * NC + c) * NHW + n];
            fused[((size_t)b * NC + c) * NHW + n] = g * cwv + lo * sw;
        }
    }
}

// out = Wo @ fused + bo + x
__global__ __launch_bounds__(256) void gemm_out(
    const float* __restrict__ Wo, const float* __restrict__ fused, const float* __restrict__ bo,
    const float* __restrict__ x, float* __restrict__ out)
{
    int n0 = blockIdx.x * 64, m0 = blockIdx.y * 64, b = blockIdx.z;
    float acc[4][4] = {};
    gemm64<256>(Wo, fused + (size_t)b * NC * NHW, m0, n0, threadIdx.x, acc);
    int tn = threadIdx.x & 15, tm = threadIdx.x >> 4;
#pragma unroll
    for (int i = 0; i < 4; i++) {
        int o = m0 + tm * 4 + i;
        float bb = bo[o];
#pragma unroll
        for (int j = 0; j < 4; j++) {
            int n = n0 + tn * 4 + j;
            size_t idx = ((size_t)b * NC + o) * NHW + n;
            out[idx] = acc[i][j] + bb + x[idx];
        }
    }
}

// ---------- bf16 transpose [C][N] -> [N][C] for q and k ----------
__global__ __launch_bounds__(256) void transpose_bf(
    const u16* __restrict__ q_bf, const u16* __restrict__ k_bf,
    u16* __restrict__ qT, u16* __restrict__ kT)
{
    __shared__ u16 tile[64][72];
    int n0 = blockIdx.x * 64, c0 = blockIdx.y * 64;
    int zb = blockIdx.z, b = zb >> 1;
    const u16* src = (zb & 1) ? k_bf : q_bf;
    u16* dst = (zb & 1) ? kT : qT;
    src += (size_t)b * NC * NHW;
    dst += (size_t)b * NHW * NC;
    int t = threadIdx.x;
    int c = t >> 2, nb = (t & 3) * 16;
    *(short8s*)&tile[c][nb]     = *(const short8s*)(src + (size_t)(c0 + c) * NHW + n0 + nb);
    *(short8s*)&tile[c][nb + 8] = *(const short8s*)(src + (size_t)(c0 + c) * NHW + n0 + nb + 8);
    __syncthreads();
    int cl = t & 63, ng = t >> 6;
#pragma unroll
    for (int j = 0; j < 16; j++) {
        int n = ng * 16 + j;
        dst[(size_t)(n0 + n) * NC + c0 + cl] = tile[cl][n];
    }
}

// ---------- staging helper: K tile + V tile (8 DMA instructions per wave) ----------
__device__ __forceinline__ void stage_tiles(
    const u16* __restrict__ kTb, const u16* __restrict__ vNb, int kv0,
    u16* KlB, u16* VlB, int w, int lane)
{
#pragma unroll
    for (int i = 0; i < 4; i++) {
        int g = (w * 4 + i) * 64 + lane;
        int n = g >> 5, jj = g & 31, cc = jj ^ n;
        load_lds16(kTb + (size_t)(kv0 + n) * NC + cc * 8, (char*)KlB + (w * 4 + i) * 1024);
    }
#pragma unroll
    for (int i = 0; i < 4; i++) {
        int g = (w * 4 + i) * 64 + lane;
        int c = g >> 2, jj = g & 3, ck = (jj - (c >> 1)) & 3;
        load_lds16(vNb + (size_t)c * NHW + kv0 + ck * 8, (char*)VlB + (w * 4 + i) * 1024);
    }
}

// ---------- flash attention, kv-split, double-buffered, XCD-swizzled ----------
// 1-D grid of 1024: combo=(b*4+jc)=blockIdx.x&15 (XCD-local), qt=blockIdx.x>>4.
__global__ __launch_bounds__(256, 2) void attn_split(
    const u16* __restrict__ qT, const u16* __restrict__ kT,
    const u16* __restrict__ vN, u16* __restrict__ Opart, float* __restrict__ lpart)
{
    __shared__ u16 Kl[2][BC * 256];   // 2 x 16KB; P aliased into consumed buffer
    __shared__ u16 Vl[2][256 * BC];   // 2 x 16KB

    const int combo = blockIdx.x & 15;
    const int b  = combo >> 2;
    const int jc = combo & 3;
    const int n0 = (blockIdx.x >> 4) * 64;
    const int t = threadIdx.x;
    const int w = t >> 6, lane = t & 63;
    const int lm = lane & 15, quad = lane >> 4;

    const size_t bQ = (size_t)b * NHW * NC;
    const u16* qTb = qT + bQ;
    const u16* kTb = kT + bQ;
    const u16* vNb = vN + bQ;

    // Q fragments (A-operand): A[m=lm][k=quad*8+j], K-dim = 256 -> 8 frags
    bf16x8 aq[8];
    {
        int qrow = n0 + w * 16 + lm;
#pragma unroll
        for (int kt = 0; kt < 8; kt++)
            aq[kt] = *(const bf16x8*)(qTb + (size_t)qrow * NC + kt * 32 + quad * 8);
    }

    float4v oacc[16];
#pragma unroll
    for (int i = 0; i < 16; i++) oacc[i] = (float4v){0.f, 0.f, 0.f, 0.f};
    float lsum[4] = {0.f, 0.f, 0.f, 0.f};

    const int kvbeg = jc * KVCHUNK;
    // prologue stage into buf 0
    stage_tiles(kTb, vNb, kvbeg, Kl[0], Vl[0], w, lane);

    int buf = 0;
#pragma unroll 1
    for (int it = 0; it < KVCHUNK / BC; it++) {
        const int kv0 = kvbeg + it * BC;
        // prefetch next tile (tail: redundant re-stage of first tile keeps vmcnt uniform)
        const int nxt = (it + 1 < KVCHUNK / BC) ? (kv0 + BC) : kvbeg;
        stage_tiles(kTb, vNb, nxt, Kl[buf ^ 1], Vl[buf ^ 1], w, lane);
        // wait current tile's 8 DMAs (leave the 8 prefetch DMAs in flight), then sync
        asm volatile("s_waitcnt vmcnt(8)" ::: "memory");
        __builtin_amdgcn_s_barrier();

        const u16* KlB = Kl[buf];
        const u16* VlB = Vl[buf];

        // S = Q @ K^T : 16x32 per wave
        float4v sf[2];
#pragma unroll
        for (int nt = 0; nt < 2; nt++) {
            float4v acc = (float4v){0.f, 0.f, 0.f, 0.f};
            int n = nt * 16 + lm;
#pragma unroll
            for (int kt = 0; kt < 8; kt++) {
                int cc = kt * 4 + quad;
                bf16x8 bk = *(const bf16x8*)&KlB[(n * 32 + (cc ^ n)) * 8];
                acc = __builtin_amdgcn_mfma_f32_16x16x32_bf16(aq[kt], bk, acc, 0, 0, 0);
            }
            sf[nt] = acc;
        }
        // exp (no max subtraction; logits bounded ~|0.2|) + row sums
        float rp[4] = {0.f, 0.f, 0.f, 0.f};
#pragma unroll
        for (int nt = 0; nt < 2; nt++)
#pragma unroll
            for (int r = 0; r < 4; r++) {
                float p = __expf(sf[nt][r] * 0.0625f);
                sf[nt][r] = p;
                rp[r] += p;
            }
#pragma unroll
        for (int off = 8; off >= 1; off >>= 1)
#pragma unroll
            for (int r = 0; r < 4; r++)
                rp[r] += __shfl_xor(rp[r], off, 64);
#pragma unroll
        for (int r = 0; r < 4; r++) lsum[r] += rp[r];

        // all waves done reading K[buf] -> safe to alias P into it
        __builtin_amdgcn_s_barrier();

        // P (C-layout) -> A-operand layout in wave-private slice of Kl[buf]
        u16* Pw = (u16*)Kl[buf] + w * 512;
#pragma unroll
        for (int nt = 0; nt < 2; nt++) {
            int col = nt * 16 + lm;
            int cg = col >> 3, cr = col & 7;
#pragma unroll
            for (int r = 0; r < 4; r++) {
                int row = quad * 4 + r;
                int sg = (cg + (row >> 1)) & 3;
                Pw[row * 32 + sg * 8 + cr] = f2b(sf[nt][r]);
            }
        }
        asm volatile("s_waitcnt lgkmcnt(0)" ::: "memory");
        // PV: O += P @ V  (K-dim = 32 -> one A frag)
        bf16x8 pa = *(const bf16x8*)&Pw[lm * 32 + (((quad + (lm >> 1)) & 3)) * 8];
#pragma unroll
        for (int ct = 0; ct < 16; ct++) {
            int c = ct * 16 + lm;
            bf16x8 bv = *(const bf16x8*)&VlB[c * 32 + (((quad + (c >> 1)) & 3)) * 8];
            oacc[ct] = __builtin_amdgcn_mfma_f32_16x16x32_bf16(pa, bv, oacc[ct], 0, 0, 0);
        }
        // all waves done reading V[buf]/P before next iter's prefetch overwrites
        __builtin_amdgcn_s_barrier();
        buf ^= 1;
    }

    // epilogue: partial O (bf16) + partial l
    u16* Ob = Opart + ((size_t)(b * NKV + jc) * NHW + n0 + w * 16) * NC;
#pragma unroll
    for (int r = 0; r < 4; r++) {
        int row = quad * 4 + r;
#pragma unroll
        for (int ct = 0; ct < 16; ct++)
            Ob[(size_t)row * NC + ct * 16 + lm] = f2b(oacc[ct][r]);
        if (lm == 0)
            lpart[(size_t)(b * NKV + jc) * NHW + n0 + w * 16 + row] = lsum[r];
    }
}

// ---------- combine kv-split partials: gT = sum(Opart)/sum(lpart) ----------
__global__ __launch_bounds__(256) void attn_combine(
    const u16* __restrict__ Opart, const float* __restrict__ lpart, float* __restrict__ gT)
{
    int b = blockIdx.y;
    int n = blockIdx.x * 8 + (threadIdx.x >> 5);
    int c0 = (threadIdx.x & 31) * 8;
    float acc[8] = {};
    float l = 0.f;
#pragma unroll
    for (int j = 0; j < NKV; j++) {
        const u16* op = Opart + ((size_t)(b * NKV + j) * NHW + n) * NC + c0;
        short8s v = *(const short8s*)op;
#pragma unroll
        for (int i = 0; i < 8; i++) acc[i] += b2f(((const u16*)&v)[i]);
        l += lpart[(size_t)(b * NKV + j) * NHW + n];
    }
    float inv = 1.0f / l;
    float* g = gT + ((size_t)b * NHW + n) * NC + c0;
#pragma unroll
    for (int i = 0; i < 8; i++) acc[i] *= inv;
    *(float4*)&g[0] = make_float4(acc[0], acc[1], acc[2], acc[3]);
    *(float4*)&g[4] = make_float4(acc[4], acc[5], acc[6], acc[7]);
}

// ---------- gap reduce + channel MLP ----------
__global__ __launch_bounds__(256) void gap_reduce(const float* __restrict__ gT, float* __restrict__ gap)
{
    int b = blockIdx.y, n0 = blockIdx.x * 64, t = threadIdx.x;
    const float* g = gT + ((size_t)b * NHW + n0) * NC;
    float acc = 0.f;
#pragma unroll 4
    for (int i = 0; i < 64; i++) acc += g[(size_t)i * NC + t];
    atomicAdd(&gap[b * NC + t], acc);
}

__global__ __launch_bounds__(256) void channel_mlp(
    const float* __restrict__ gap, const float* __restrict__ Wc1, const float* __restrict__ bc1,
    const float* __restrict__ Wc2, const float* __restrict__ bc2, float* __restrict__ cw)
{
    __shared__ float g[256];
    __shared__ float ph[32][9];
    __shared__ float h1[32];
    int t = threadIdx.x;
    for (int b = 0; b < 4; b++) {
        g[t] = gap[b * 256 + t] * (1.0f / 4096.0f);
        __syncthreads();
        {
            int h = t & 31, part = t >> 5;
            float s = 0.f;
            for (int c = part * 32; c < part * 32 + 32; c++) s += Wc1[h * 256 + c] * g[c];
            ph[h][part] = s;
        }
        __syncthreads();
        if (t < 32) {
            float s = bc1[t];
#pragma unroll
            for (int p = 0; p < 8; p++) s += ph[t][p];
            h1[t] = fmaxf(s, 0.f);
        }
        __syncthreads();
        float s = bc2[t];
#pragma unroll
        for (int j = 0; j < 32; j++) s += Wc2[t * 32 + j] * h1[j];
        cw[b * 256 + t] = 1.0f / (1.0f + __expf(-s));
        __syncthreads();
    }
}

extern "C" void kernel_launch(void* const* d_in, const int* in_sizes, int n_in,
                              void* d_out, int out_size, void* d_ws, size_t ws_size,
                              hipStream_t stream)
{
    const float* x   = (const float*)d_in[0];
    const float* Wq  = (const float*)d_in[1];
    const float* bq  = (const float*)d_in[2];
    const float* Wk  = (const float*)d_in[3];
    const float* bk  = (const float*)d_in[4];
    const float* Wv  = (const float*)d_in[5];
    const float* bv  = (const float*)d_in[6];
    const float* Wl  = (const float*)d_in[7];
    const float* bl  = (const float*)d_in[8];
    const float* Ws1 = (const float*)d_in[9];
    const float* bs1 = (const float*)d_in[10];
    const float* Ws2 = (const float*)d_in[11];
    const float* bs2 = (const float*)d_in[12];
    const float* Wc1 = (const float*)d_in[13];
    const float* bc1 = (const float*)d_in[14];
    const float* Wc2 = (const float*)d_in[15];
    const float* bc2 = (const float*)d_in[16];
    const float* Wo  = (const float*)d_in[17];
    const float* bo  = (const float*)d_in[18];
    float* out = (float*)d_out;

    char* ws = (char*)d_ws;
    u16* k_bf = (u16*)(ws + OFF_KBF);
    u16* vN   = (u16*)(ws + OFF_VBF);
    u16* q_bf = (u16*)(ws + OFF_QBF);
    u16* qT   = (u16*)(ws + OFF_QT);
    u16* kT   = (u16*)(ws + OFF_KT);
    float* gT    = (float*)(ws + OFF_GT);
    float* local = (float*)(ws + OFF_LOCAL);
    float* hid   = (float*)(ws + OFF_HID);
    float* fused = (float*)(ws + OFF_FUSED);
    float* gap   = (float*)(ws + OFF_GAP);
    float* cw    = (float*)(ws + OFF_CW);
    u16* Opart   = (u16*)(ws + OFF_OPART);
    float* lpart = (float*)(ws + OFF_LPART);

    dw_kv<<<dim3(64, 64, 4), 256, 0, stream>>>(x, Wk, bk, Wv, bv, k_bf, vN);
    gemm_q<<<dim3(64, 4, 4), 256, 0, stream>>>(Wq, x, bq, q_bf);
    transpose_bf<<<dim3(64, 4, 8), 256, 0, stream>>>(q_bf, k_bf, qT, kT);
    dw_local<<<dim3(64, 64, 4), 256, 0, stream>>>(vN, Wl, bl, local);
    attn_split<<<dim3(1024), 256, 0, stream>>>(qT, kT, vN, Opart, lpart);
    attn_combine<<<dim3(NHW / 8, 4), 256, 0, stream>>>(Opart, lpart, gT);
    hipMemsetAsync(gap, 0, NB * NC * sizeof(float), stream);
    gap_reduce<<<dim3(64, 4), 256, 0, stream>>>(gT, gap);
    channel_mlp<<<1, 256, 0, stream>>>(gap, Wc1, bc1, Wc2, bc2, cw);
    gemm_hid<<<dim3(64, 1, 4), 256, 0, stream>>>(Ws1, local, bs1, hid);
    gemm_swfused<<<dim3(64, 4, 4), 256, 0, stream>>>(Ws2, hid, bs2, gT, local, cw, fused);
    gemm_out<<<dim3(64, 4, 4), 256, 0, stream>>>(Wo, fused, bo, x, out);
}

// Round 4
// 389.324 us; speedup vs baseline: 1.7646x; 1.0440x over previous
//
#include <hip/hip_runtime.h>
#include <stdint.h>

typedef unsigned short u16;
typedef __attribute__((ext_vector_type(8))) __bf16 bf16x8;
typedef __attribute__((ext_vector_type(8))) short short8s;
typedef __attribute__((ext_vector_type(4))) float float4v;

// ---------- sizes ----------
static constexpr int NB = 4, NC = 256, NH = 64, NW = 64, NHW = 4096;
static constexpr int BC = 32;        // kv tile
static constexpr int NKV = 4;        // kv split factor
static constexpr int KVCHUNK = NHW / NKV;   // 1024

// ---------- workspace layout (lifetime-aliased, ~91MB) ----------
static constexpr size_t MB = 1ull << 20;
static constexpr size_t OFF_KBF    = 0;          // bf16 [B][C][N] 8MB (dead after transpose)
static constexpr size_t OFF_LBF    = 8 * MB;     // bf16 [B][C][N] 8MB (dead after transpose)
static constexpr size_t OFF_GT     = 0;          // fp32 [B][N][C] 16MB — overlays KBF+LBF (written by combine)
static constexpr size_t OFF_XT     = 16 * MB;    // bf16 [B][N][C] 8MB (dead after gemm_q)
static constexpr size_t OFF_FUSEDT = 16 * MB;    // bf16 [B][N][C] 8MB — overlays XT (written by swfused)
static constexpr size_t OFF_QT     = 24 * MB;    // bf16 [B][N][C] 8MB
static constexpr size_t OFF_KT     = 32 * MB;    // bf16 [B][N][C] 8MB
static constexpr size_t OFF_VBF    = 40 * MB;    // bf16 [B][C][N] 8MB
static constexpr size_t OFF_LT     = 48 * MB;    // bf16 [B][N][C] 8MB (localT, live to swfused)
static constexpr size_t OFF_OPART  = 56 * MB;    // bf16 [B][NKV][N][C] 32MB
static constexpr size_t OFF_LPART  = 88 * MB;    // fp32 [B][NKV][N] 256KB
static constexpr size_t OFF_HIDT   = OFF_LPART + 256 * 1024;   // bf16 [B][N][64] 2MB
static constexpr size_t OFF_GAP    = OFF_HIDT + 2 * MB;        // fp32 [B][256]
static constexpr size_t OFF_CW     = OFF_GAP + 8 * 1024;       // fp32 [B][256]
static constexpr size_t OFF_WQB    = OFF_CW + 8 * 1024;        // bf16 256x256
static constexpr size_t OFF_WS1B   = OFF_WQB + 131072;         // bf16 64x256
static constexpr size_t OFF_WS2B   = OFF_WS1B + 32768;         // bf16 256x64
static constexpr size_t OFF_WOB    = OFF_WS2B + 32768;         // bf16 256x256

__device__ __forceinline__ float b2f(u16 h) {
    union { float f; unsigned u; } v; v.u = ((unsigned)h) << 16; return v.f;
}
__device__ __forceinline__ u16 f2b(float f) {
    union { float f; unsigned u; } v; v.f = f;
    unsigned r = v.u + 0x7fffu + ((v.u >> 16) & 1u);
    return (u16)(r >> 16);
}

// async global->LDS, 16B per lane; ldst must be wave-uniform (HW adds lane*16)
__device__ __forceinline__ void load_lds16(const void* gsrc, void* ldst) {
    __builtin_amdgcn_global_load_lds(
        (__attribute__((address_space(1))) void*)(uintptr_t)gsrc,
        (__attribute__((address_space(3))) void*)ldst,
        16, 0, 0);
}

// ---------- weight fp32->bf16 conversion (one-shot, tiny) ----------
__global__ __launch_bounds__(256) void convert_weights(
    const float* __restrict__ Wq, const float* __restrict__ Ws1,
    const float* __restrict__ Ws2, const float* __restrict__ Wo,
    u16* __restrict__ Wqb, u16* __restrict__ Ws1b, u16* __restrict__ Ws2b, u16* __restrict__ Wob)
{
    int id = blockIdx.x * 256 + threadIdx.x;
    if (id < 65536)        Wqb[id] = f2b(Wq[id]);
    else if (id < 81920)   Ws1b[id - 65536] = f2b(Ws1[id - 65536]);
    else if (id < 98304)   Ws2b[id - 81920] = f2b(Ws2[id - 81920]);
    else                   Wob[id - 98304] = f2b(Wo[id - 98304]);
}

// ---------- depthwise 3x3: k and v (bf16 outputs) ----------
__global__ __launch_bounds__(256) void dw_kv(
    const float* __restrict__ x, const float* __restrict__ Wk, const float* __restrict__ bk,
    const float* __restrict__ Wv, const float* __restrict__ bv,
    u16* __restrict__ k_bf, u16* __restrict__ vN)
{
    int t = threadIdx.x;
    int xx0 = t & 63, cl = t >> 6;
    int y  = blockIdx.x;
    int c  = blockIdx.y * 4 + cl;
    int b  = blockIdx.z;
    const float* xb = x + ((size_t)b * NC + c) * NHW;
    float wk[9], wv[9];
#pragma unroll
    for (int i = 0; i < 9; i++) { wk[i] = Wk[c * 9 + i]; wv[i] = Wv[c * 9 + i]; }
    float ak = bk[c], av = bv[c];
#pragma unroll
    for (int ky = 0; ky < 3; ky++) {
        int yy = y + ky - 1;
        if (yy < 0 || yy > 63) continue;
#pragma unroll
        for (int kx = 0; kx < 3; kx++) {
            int xx = xx0 + kx - 1;
            if (xx < 0 || xx > 63) continue;
            float xv = xb[yy * 64 + xx];
            ak += wk[ky * 3 + kx] * xv;
            av += wv[ky * 3 + kx] * xv;
        }
    }
    size_t o = ((size_t)b * NC + c) * NHW + y * 64 + xx0;
    k_bf[o] = f2b(ak);
    vN[o]   = f2b(av);
}

// ---------- depthwise 3x3 on v (bf16 in, bf16 out) ----------
__global__ __launch_bounds__(256) void dw_local(
    const u16* __restrict__ vN, const float* __restrict__ Wl, const float* __restrict__ bl,
    u16* __restrict__ local_bf)
{
    int t = threadIdx.x;
    int xx0 = t & 63, cl = t >> 6;
    int y = blockIdx.x;
    int c = blockIdx.y * 4 + cl;
    int b = blockIdx.z;
    const u16* vb = vN + ((size_t)b * NC + c) * NHW;
    float wl[9];
#pragma unroll
    for (int i = 0; i < 9; i++) wl[i] = Wl[c * 9 + i];
    float a = bl[c];
#pragma unroll
    for (int ky = 0; ky < 3; ky++) {
        int yy = y + ky - 1;
        if (yy < 0 || yy > 63) continue;
#pragma unroll
        for (int kx = 0; kx < 3; kx++) {
            int xx = xx0 + kx - 1;
            if (xx < 0 || xx > 63) continue;
            a += wl[ky * 3 + kx] * b2f(vb[yy * 64 + xx]);
        }
    }
    local_bf[((size_t)b * NC + c) * NHW + y * 64 + xx0] = f2b(a);
}

// ---------- bf16 transpose [C][N] -> [N][C] for k and local ----------
__global__ __launch_bounds__(256) void transpose_bf(
    const u16* __restrict__ k_bf, const u16* __restrict__ local_bf,
    u16* __restrict__ kT, u16* __restrict__ localT)
{
    __shared__ u16 tile[64][72];
    int n0 = blockIdx.x * 64, c0 = blockIdx.y * 64;
    int zb = blockIdx.z, b = zb >> 1;
    const u16* src = (zb & 1) ? local_bf : k_bf;
    u16* dst = (zb & 1) ? localT : kT;
    src += (size_t)b * NC * NHW;
    dst += (size_t)b * NHW * NC;
    int t = threadIdx.x;
    int c = t >> 2, nb = (t & 3) * 16;
    *(short8s*)&tile[c][nb]     = *(const short8s*)(src + (size_t)(c0 + c) * NHW + n0 + nb);
    *(short8s*)&tile[c][nb + 8] = *(const short8s*)(src + (size_t)(c0 + c) * NHW + n0 + nb + 8);
    __syncthreads();
    int cl = t & 63, ng = t >> 6;
#pragma unroll
    for (int j = 0; j < 16; j++) {
        int n = ng * 16 + j;
        dst[(size_t)(n0 + n) * NC + c0 + cl] = tile[cl][n];
    }
}

// ---------- fp32 [C][N] -> bf16 [N][C] transpose-convert for x ----------
__global__ __launch_bounds__(256) void transpose_f2b(
    const float* __restrict__ x, u16* __restrict__ xT)
{
    __shared__ u16 tile[64][72];
    int n0 = blockIdx.x * 64, c0 = blockIdx.y * 64, b = blockIdx.z;
    const float* src = x + (size_t)b * NC * NHW;
    u16* dst = xT + (size_t)b * NHW * NC;
    int t = threadIdx.x;
    int c = t >> 2, nb = (t & 3) * 16;
#pragma unroll
    for (int q = 0; q < 4; q++) {
        float4 v = *(const float4*)(src + (size_t)(c0 + c) * NHW + n0 + nb + q * 4);
        tile[c][nb + q * 4 + 0] = f2b(v.x);
        tile[c][nb + q * 4 + 1] = f2b(v.y);
        tile[c][nb + q * 4 + 2] = f2b(v.z);
        tile[c][nb + q * 4 + 3] = f2b(v.w);
    }
    __syncthreads();
    int cl = t & 63, ng = t >> 6;
#pragma unroll
    for (int j = 0; j < 16; j++) {
        int n = ng * 16 + j;
        dst[(size_t)(n0 + n) * NC + c0 + cl] = tile[cl][n];
    }
}

// ---------- MFMA GEMM: qT[n][cout] = xT[n][:] . Wq[cout][:] + bq ----------
// grid (128 n-blocks of 32, B). wave: 16 n-rows x 128 couts.
__global__ __launch_bounds__(256) void gemm_q_mfma(
    const u16* __restrict__ xT, const u16* __restrict__ Wqb, const float* __restrict__ bq,
    u16* __restrict__ qT)
{
    const int t = threadIdx.x, w = t >> 6, lane = t & 63;
    const int lm = lane & 15, quad = lane >> 4;
    const int b = blockIdx.y;
    const int s_base = blockIdx.x * 32 + (w & 1) * 16;
    const int ch = (w >> 1) * 128;
    const u16* xTb = xT + (size_t)b * NHW * NC;
    u16* qTb = qT + (size_t)b * NHW * NC;

    bf16x8 aq[8];
#pragma unroll
    for (int kt = 0; kt < 8; kt++)
        aq[kt] = *(const bf16x8*)(xTb + (size_t)(s_base + lm) * NC + kt * 32 + quad * 8);

    float4v acc[8];
#pragma unroll
    for (int j = 0; j < 8; j++) acc[j] = (float4v){0.f, 0.f, 0.f, 0.f};

#pragma unroll
    for (int kt = 0; kt < 8; kt++) {
#pragma unroll
        for (int j = 0; j < 8; j++) {
            bf16x8 bw = *(const bf16x8*)(Wqb + (size_t)(ch + j * 16 + lm) * 256 + kt * 32 + quad * 8);
            acc[j] = __builtin_amdgcn_mfma_f32_16x16x32_bf16(aq[kt], bw, acc[j], 0, 0, 0);
        }
    }
#pragma unroll
    for (int j = 0; j < 8; j++) {
        int cout = ch + j * 16 + lm;
        float bb = bq[cout];
#pragma unroll
        for (int r = 0; r < 4; r++) {
            int s = s_base + quad * 4 + r;
            qTb[(size_t)s * NC + cout] = f2b(acc[j][r] + bb);
        }
    }
}

// ---------- MFMA GEMM: hidT[n][h] = relu(localT[n][:] . Ws1[h][:] + bs1) ----------
__global__ __launch_bounds__(256) void gemm_hid_mfma(
    const u16* __restrict__ localT, const u16* __restrict__ Ws1b, const float* __restrict__ bs1,
    u16* __restrict__ hidT)
{
    const int t = threadIdx.x, w = t >> 6, lane = t & 63;
    const int lm = lane & 15, quad = lane >> 4;
    const int b = blockIdx.y;
    const int s_base = blockIdx.x * 32 + (w & 1) * 16;
    const int ch = (w >> 1) * 32;
    const u16* lTb = localT + (size_t)b * NHW * NC;
    u16* hTb = hidT + (size_t)b * NHW * 64;

    bf16x8 aq[8];
#pragma unroll
    for (int kt = 0; kt < 8; kt++)
        aq[kt] = *(const bf16x8*)(lTb + (size_t)(s_base + lm) * NC + kt * 32 + quad * 8);

    float4v acc[2];
#pragma unroll
    for (int j = 0; j < 2; j++) acc[j] = (float4v){0.f, 0.f, 0.f, 0.f};

#pragma unroll
    for (int kt = 0; kt < 8; kt++) {
#pragma unroll
        for (int j = 0; j < 2; j++) {
            bf16x8 bw = *(const bf16x8*)(Ws1b + (size_t)(ch + j * 16 + lm) * 256 + kt * 32 + quad * 8);
            acc[j] = __builtin_amdgcn_mfma_f32_16x16x32_bf16(aq[kt], bw, acc[j], 0, 0, 0);
        }
    }
#pragma unroll
    for (int j = 0; j < 2; j++) {
        int h = ch + j * 16 + lm;
        float bb = bs1[h];
#pragma unroll
        for (int r = 0; r < 4; r++) {
            int s = s_base + quad * 4 + r;
            hTb[(size_t)s * 64 + h] = f2b(fmaxf(acc[j][r] + bb, 0.0f));
        }
    }
}

// ---------- MFMA GEMM + fuse: fusedT[n][c] = gT*cw + localT*sigmoid(hidT.Ws2^T + bs2) ----------
__global__ __launch_bounds__(256) void gemm_swfused_mfma(
    const u16* __restrict__ hidT, const u16* __restrict__ Ws2b, const float* __restrict__ bs2,
    const float* __restrict__ gT, const u16* __restrict__ localT, const float* __restrict__ cw,
    u16* __restrict__ fusedT)
{
    const int t = threadIdx.x, w = t >> 6, lane = t & 63;
    const int lm = lane & 15, quad = lane >> 4;
    const int b = blockIdx.y;
    const int s_base = blockIdx.x * 32 + (w & 1) * 16;
    const int ch = (w >> 1) * 128;
    const u16* hTb = hidT + (size_t)b * NHW * 64;
    const u16* lTb = localT + (size_t)b * NHW * NC;
    const float* gTb = gT + (size_t)b * NHW * NC;
    u16* fTb = fusedT + (size_t)b * NHW * NC;

    bf16x8 aq[2];
#pragma unroll
    for (int kt = 0; kt < 2; kt++)
        aq[kt] = *(const bf16x8*)(hTb + (size_t)(s_base + lm) * 64 + kt * 32 + quad * 8);

    float4v acc[8];
#pragma unroll
    for (int j = 0; j < 8; j++) acc[j] = (float4v){0.f, 0.f, 0.f, 0.f};

#pragma unroll
    for (int kt = 0; kt < 2; kt++) {
#pragma unroll
        for (int j = 0; j < 8; j++) {
            bf16x8 bw = *(const bf16x8*)(Ws2b + (size_t)(ch + j * 16 + lm) * 64 + kt * 32 + quad * 8);
            acc[j] = __builtin_amdgcn_mfma_f32_16x16x32_bf16(aq[kt], bw, acc[j], 0, 0, 0);
        }
    }
#pragma unroll
    for (int j = 0; j < 8; j++) {
        int c = ch + j * 16 + lm;
        float bb = bs2[c];
        float cwv = cw[b * NC + c];
#pragma unroll
        for (int r = 0; r < 4; r++) {
            int s = s_base + quad * 4 + r;
            float sw = 1.0f / (1.0f + __expf(-(acc[j][r] + bb)));
            float g = gTb[(size_t)s * NC + c];
            float lo = b2f(lTb[(size_t)s * NC + c]);
            fTb[(size_t)s * NC + c] = f2b(g * cwv + lo * sw);
        }
    }
}

// ---------- MFMA GEMM: out[o][n] = Wo[o][:] . fusedT[n][:] + bo + x ----------
// grid (8 o-blocks of 32, 16 n-blocks of 256, B). wave: 16 o-rows x 128 n.
__global__ __launch_bounds__(256) void gemm_out_mfma(
    const u16* __restrict__ Wob, const u16* __restrict__ fusedT, const float* __restrict__ bo,
    const float* __restrict__ x, float* __restrict__ out)
{
    const int t = threadIdx.x, w = t >> 6, lane = t & 63;
    const int lm = lane & 15, quad = lane >> 4;
    const int b = blockIdx.z;
    const int o_base = blockIdx.x * 32 + (w & 1) * 16;
    const int n_base = blockIdx.y * 256 + (w >> 1) * 128;
    const u16* fTb = fusedT + (size_t)b * NHW * NC;

    bf16x8 aw[8];
#pragma unroll
    for (int kt = 0; kt < 8; kt++)
        aw[kt] = *(const bf16x8*)(Wob + (size_t)(o_base + lm) * 256 + kt * 32 + quad * 8);

    float4v acc[8];
#pragma unroll
    for (int j = 0; j < 8; j++) acc[j] = (float4v){0.f, 0.f, 0.f, 0.f};

#pragma unroll
    for (int kt = 0; kt < 8; kt++) {
#pragma unroll
        for (int j = 0; j < 8; j++) {
            bf16x8 bf = *(const bf16x8*)(fTb + (size_t)(n_base + j * 16 + lm) * NC + kt * 32 + quad * 8);
            acc[j] = __builtin_amdgcn_mfma_f32_16x16x32_bf16(aw[kt], bf, acc[j], 0, 0, 0);
        }
    }
#pragma unroll
    for (int r = 0; r < 4; r++) {
        int o = o_base + quad * 4 + r;
        float bb = bo[o];
        size_t rowoff = ((size_t)b * NC + o) * NHW;
#pragma unroll
        for (int j = 0; j < 8; j++) {
            int n = n_base + j * 16 + lm;
            out[rowoff + n] = acc[j][r] + bb + x[rowoff + n];
        }
    }
}

// ---------- staging helper: K tile + V tile (8 DMA instructions per wave) ----------
__device__ __forceinline__ void stage_tiles(
    const u16* __restrict__ kTb, const u16* __restrict__ vNb, int kv0,
    u16* KlB, u16* VlB, int w, int lane)
{
#pragma unroll
    for (int i = 0; i < 4; i++) {
        int g = (w * 4 + i) * 64 + lane;
        int n = g >> 5, jj = g & 31, cc = jj ^ n;
        load_lds16(kTb + (size_t)(kv0 + n) * NC + cc * 8, (char*)KlB + (w * 4 + i) * 1024);
    }
#pragma unroll
    for (int i = 0; i < 4; i++) {
        int g = (w * 4 + i) * 64 + lane;
        int c = g >> 2, jj = g & 3, ck = (jj - (c >> 1)) & 3;
        load_lds16(vNb + (size_t)c * NHW + kv0 + ck * 8, (char*)VlB + (w * 4 + i) * 1024);
    }
}

// ---------- flash attention, kv-split, double-buffered, XCD-swizzled ----------
__global__ __launch_bounds__(256, 2) void attn_split(
    const u16* __restrict__ qT, const u16* __restrict__ kT,
    const u16* __restrict__ vN, u16* __restrict__ Opart, float* __restrict__ lpart)
{
    __shared__ u16 Kl[2][BC * 256];   // 2 x 16KB; P aliased into consumed buffer
    __shared__ u16 Vl[2][256 * BC];   // 2 x 16KB

    const int combo = blockIdx.x & 15;
    const int b  = combo >> 2;
    const int jc = combo & 3;
    const int n0 = (blockIdx.x >> 4) * 64;
    const int t = threadIdx.x;
    const int w = t >> 6, lane = t & 63;
    const int lm = lane & 15, quad = lane >> 4;

    const size_t bQ = (size_t)b * NHW * NC;
    const u16* qTb = qT + bQ;
    const u16* kTb = kT + bQ;
    const u16* vNb = vN + bQ;

    bf16x8 aq[8];
    {
        int qrow = n0 + w * 16 + lm;
#pragma unroll
        for (int kt = 0; kt < 8; kt++)
            aq[kt] = *(const bf16x8*)(qTb + (size_t)qrow * NC + kt * 32 + quad * 8);
    }

    float4v oacc[16];
#pragma unroll
    for (int i = 0; i < 16; i++) oacc[i] = (float4v){0.f, 0.f, 0.f, 0.f};
    float lsum[4] = {0.f, 0.f, 0.f, 0.f};

    const int kvbeg = jc * KVCHUNK;
    stage_tiles(kTb, vNb, kvbeg, Kl[0], Vl[0], w, lane);

    int buf = 0;
#pragma unroll 1
    for (int it = 0; it < KVCHUNK / BC; it++) {
        const int kv0 = kvbeg + it * BC;
        const int nxt = (it + 1 < KVCHUNK / BC) ? (kv0 + BC) : kvbeg;
        stage_tiles(kTb, vNb, nxt, Kl[buf ^ 1], Vl[buf ^ 1], w, lane);
        asm volatile("s_waitcnt vmcnt(8)" ::: "memory");
        __builtin_amdgcn_s_barrier();

        const u16* KlB = Kl[buf];
        const u16* VlB = Vl[buf];

        float4v sf[2];
#pragma unroll
        for (int nt = 0; nt < 2; nt++) {
            float4v acc = (float4v){0.f, 0.f, 0.f, 0.f};
            int n = nt * 16 + lm;
#pragma unroll
            for (int kt = 0; kt < 8; kt++) {
                int cc = kt * 4 + quad;
                bf16x8 bk = *(const bf16x8*)&KlB[(n * 32 + (cc ^ n)) * 8];
                acc = __builtin_amdgcn_mfma_f32_16x16x32_bf16(aq[kt], bk, acc, 0, 0, 0);
            }
            sf[nt] = acc;
        }
        float rp[4] = {0.f, 0.f, 0.f, 0.f};
#pragma unroll
        for (int nt = 0; nt < 2; nt++)
#pragma unroll
            for (int r = 0; r < 4; r++) {
                float p = __expf(sf[nt][r] * 0.0625f);
                sf[nt][r] = p;
                rp[r] += p;
            }
#pragma unroll
        for (int off = 8; off >= 1; off >>= 1)
#pragma unroll
            for (int r = 0; r < 4; r++)
                rp[r] += __shfl_xor(rp[r], off, 64);
#pragma unroll
        for (int r = 0; r < 4; r++) lsum[r] += rp[r];

        __builtin_amdgcn_s_barrier();

        u16* Pw = (u16*)Kl[buf] + w * 512;
#pragma unroll
        for (int nt = 0; nt < 2; nt++) {
            int col = nt * 16 + lm;
            int cg = col >> 3, cr = col & 7;
#pragma unroll
            for (int r = 0; r < 4; r++) {
                int row = quad * 4 + r;
                int sg = (cg + (row >> 1)) & 3;
                Pw[row * 32 + sg * 8 + cr] = f2b(sf[nt][r]);
            }
        }
        asm volatile("s_waitcnt lgkmcnt(0)" ::: "memory");
        bf16x8 pa = *(const bf16x8*)&Pw[lm * 32 + (((quad + (lm >> 1)) & 3)) * 8];
#pragma unroll
        for (int ct = 0; ct < 16; ct++) {
            int c = ct * 16 + lm;
            bf16x8 bv = *(const bf16x8*)&VlB[c * 32 + (((quad + (c >> 1)) & 3)) * 8];
            oacc[ct] = __builtin_amdgcn_mfma_f32_16x16x32_bf16(pa, bv, oacc[ct], 0, 0, 0);
        }
        __builtin_amdgcn_s_barrier();
        buf ^= 1;
    }

    u16* Ob = Opart + ((size_t)(b * NKV + jc) * NHW + n0 + w * 16) * NC;
#pragma unroll
    for (int r = 0; r < 4; r++) {
        int row = quad * 4 + r;
#pragma unroll
        for (int ct = 0; ct < 16; ct++)
            Ob[(size_t)row * NC + ct * 16 + lm] = f2b(oacc[ct][r]);
        if (lm == 0)
            lpart[(size_t)(b * NKV + jc) * NHW + n0 + w * 16 + row] = lsum[r];
    }
}

// ---------- combine kv-split partials + fused gap reduce ----------
__global__ __launch_bounds__(256) void attn_combine(
    const u16* __restrict__ Opart, const float* __restrict__ lpart,
    float* __restrict__ gT, float* __restrict__ gap)
{
    __shared__ float gsum[256];
    int t = threadIdx.x;
    gsum[t] = 0.f;
    __syncthreads();
    int b = blockIdx.y;
    int n = blockIdx.x * 8 + (t >> 5);
    int c0 = (t & 31) * 8;
    float acc[8] = {};
    float l = 0.f;
#pragma unroll
    for (int j = 0; j < NKV; j++) {
        const u16* op = Opart + ((size_t)(b * NKV + j) * NHW + n) * NC + c0;
        short8s v = *(const short8s*)op;
#pragma unroll
        for (int i = 0; i < 8; i++) acc[i] += b2f(((const u16*)&v)[i]);
        l += lpart[(size_t)(b * NKV + j) * NHW + n];
    }
    float inv = 1.0f / l;
    float* g = gT + ((size_t)b * NHW + n) * NC + c0;
#pragma unroll
    for (int i = 0; i < 8; i++) acc[i] *= inv;
    *(float4*)&g[0] = make_float4(acc[0], acc[1], acc[2], acc[3]);
    *(float4*)&g[4] = make_float4(acc[4], acc[5], acc[6], acc[7]);
#pragma unroll
    for (int i = 0; i < 8; i++) atomicAdd(&gsum[c0 + i], acc[i]);
    __syncthreads();
    atomicAdd(&gap[b * NC + t], gsum[t]);
}

// ---------- channel MLP ----------
__global__ __launch_bounds__(256) void channel_mlp(
    const float* __restrict__ gap, const float* __restrict__ Wc1, const float* __restrict__ bc1,
    const float* __restrict__ Wc2, const float* __restrict__ bc2, float* __restrict__ cw)
{
    __shared__ float g[256];
    __shared__ float ph[32][9];
    __shared__ float h1[32];
    int t = threadIdx.x;
    for (int b = 0; b < 4; b++) {
        g[t] = gap[b * 256 + t] * (1.0f / 4096.0f);
        __syncthreads();
        {
            int h = t & 31, part = t >> 5;
            float s = 0.f;
            for (int c = part * 32; c < part * 32 + 32; c++) s += Wc1[h * 256 + c] * g[c];
            ph[h][part] = s;
        }
        __syncthreads();
        if (t < 32) {
            float s = bc1[t];
#pragma unroll
            for (int p = 0; p < 8; p++) s += ph[t][p];
            h1[t] = fmaxf(s, 0.f);
        }
        __syncthreads();
        float s = bc2[t];
#pragma unroll
        for (int j = 0; j < 32; j++) s += Wc2[t * 32 + j] * h1[j];
        cw[b * 256 + t] = 1.0f / (1.0f + __expf(-s));
        __syncthreads();
    }
}

extern "C" void kernel_launch(void* const* d_in, const int* in_sizes, int n_in,
                              void* d_out, int out_size, void* d_ws, size_t ws_size,
                              hipStream_t stream)
{
    const float* x   = (const float*)d_in[0];
    const float* Wq  = (const float*)d_in[1];
    const float* bq  = (const float*)d_in[2];
    const float* Wk  = (const float*)d_in[3];
    const float* bk  = (const float*)d_in[4];
    const float* Wv  = (const float*)d_in[5];
    const float* bv  = (const float*)d_in[6];
    const float* Wl  = (const float*)d_in[7];
    const float* bl  = (const float*)d_in[8];
    const float* Ws1 = (const float*)d_in[9];
    const float* bs1 = (const float*)d_in[10];
    const float* Ws2 = (const float*)d_in[11];
    const float* bs2 = (const float*)d_in[12];
    const float* Wc1 = (const float*)d_in[13];
    const float* bc1 = (const float*)d_in[14];
    const float* Wc2 = (const float*)d_in[15];
    const float* bc2 = (const float*)d_in[16];
    const float* Wo  = (const float*)d_in[17];
    const float* bo  = (const float*)d_in[18];
    float* out = (float*)d_out;

    char* ws = (char*)d_ws;
    u16* k_bf   = (u16*)(ws + OFF_KBF);
    u16* local_bf = (u16*)(ws + OFF_LBF);
    float* gT   = (float*)(ws + OFF_GT);
    u16* xT     = (u16*)(ws + OFF_XT);
    u16* fusedT = (u16*)(ws + OFF_FUSEDT);
    u16* qT     = (u16*)(ws + OFF_QT);
    u16* kT     = (u16*)(ws + OFF_KT);
    u16* vN     = (u16*)(ws + OFF_VBF);
    u16* localT = (u16*)(ws + OFF_LT);
    u16* Opart  = (u16*)(ws + OFF_OPART);
    float* lpart = (float*)(ws + OFF_LPART);
    u16* hidT   = (u16*)(ws + OFF_HIDT);
    float* gap  = (float*)(ws + OFF_GAP);
    float* cw   = (float*)(ws + OFF_CW);
    u16* Wqb    = (u16*)(ws + OFF_WQB);
    u16* Ws1b   = (u16*)(ws + OFF_WS1B);
    u16* Ws2b   = (u16*)(ws + OFF_WS2B);
    u16* Wob    = (u16*)(ws + OFF_WOB);

    convert_weights<<<dim3(640), 256, 0, stream>>>(Wq, Ws1, Ws2, Wo, Wqb, Ws1b, Ws2b, Wob);
    dw_kv<<<dim3(64, 64, 4), 256, 0, stream>>>(x, Wk, bk, Wv, bv, k_bf, vN);
    dw_local<<<dim3(64, 64, 4), 256, 0, stream>>>(vN, Wl, bl, local_bf);
    transpose_bf<<<dim3(64, 4, 8), 256, 0, stream>>>(k_bf, local_bf, kT, localT);
    transpose_f2b<<<dim3(64, 4, 4), 256, 0, stream>>>(x, xT);
    gemm_q_mfma<<<dim3(128, 4), 256, 0, stream>>>(xT, Wqb, bq, qT);
    gemm_hid_mfma<<<dim3(128, 4), 256, 0, stream>>>(localT, Ws1b, bs1, hidT);
    attn_split<<<dim3(1024), 256, 0, stream>>>(qT, kT, vN, Opart, lpart);
    hipMemsetAsync(gap, 0, NB * NC * sizeof(float), stream);
    attn_combine<<<dim3(NHW / 8, 4), 256, 0, stream>>>(Opart, lpart, gT, gap);
    channel_mlp<<<1, 256, 0, stream>>>(gap, Wc1, bc1, Wc2, bc2, cw);
    gemm_swfused_mfma<<<dim3(128, 4), 256, 0, stream>>>(hidT, Ws2b, bs2, gT, localT, cw, fusedT);
    gemm_out_mfma<<<dim3(8, 16, 4), 256, 0, stream>>>(Wob, fusedT, bo, x, out);
}